// Round 1
// baseline (20999.110 us; speedup 1.0000x reference)
//
#include <hip/hip_runtime.h>

#define NN 50000
#define TE 48
#define TF 24
#define HD 64
#define DEG 32
#define EE (NN*DEG)
#define HW 31      // hist width: 6 warmup + 1 y_prev + 24 outputs
#define PAD 68     // LDS row stride in floats (68 = 4-aligned, 17*4 -> conflict-free)

struct GruP {
    const float *w0i, *w0h, *b0i, *b0h;
    const float *w1i, *w1h, *b1i, *b1h;
    const float *o1w, *o1b, *o2w, *o2b;
};

__device__ __forceinline__ float sigf(float x) {
    return 1.f / (1.f + __expf(-x));
}
__device__ __forceinline__ float tanhfast(float x) {
    float t = __expf(-2.f * fabsf(x));   // t in (0,1], no overflow
    float r = (1.f - t) / (1.f + t);
    return x < 0.f ? -r : r;
}

// One 2-layer GRU step + output head for 64 nodes (one per lane), 8 waves.
// h0/h1: LDS [64][PAD], updated in place. red: LDS [8][64].
// Returns head output y for this lane's node (same value in all waves).
__device__ __forceinline__ float gru2_step(int lane, int wv, float x,
        float* h0, float* h1, float* red, const GruP& P)
{
    const int hr0 = wv * 8;

    // ---------- layer 0 (input dim 1) ----------
    float hn0[8];
    #pragma unroll
    for (int g = 0; g < 2; ++g) {
        const int hb = hr0 + g * 4;
        float ar[4] = {0.f,0.f,0.f,0.f}, az[4] = {0.f,0.f,0.f,0.f}, an[4] = {0.f,0.f,0.f,0.f};
        for (int kc = 0; kc < 16; ++kc) {
            float4 h4 = *(const float4*)&h0[lane * PAD + kc * 4];
            #pragma unroll
            for (int hh = 0; hh < 4; ++hh) {
                const int row = hb + hh;
                float4 wr = *(const float4*)&P.w0h[(row      ) * HD + kc * 4];
                float4 wz = *(const float4*)&P.w0h[(row +  64) * HD + kc * 4];
                float4 wn = *(const float4*)&P.w0h[(row + 128) * HD + kc * 4];
                ar[hh] = fmaf(wr.x,h4.x, fmaf(wr.y,h4.y, fmaf(wr.z,h4.z, fmaf(wr.w,h4.w, ar[hh]))));
                az[hh] = fmaf(wz.x,h4.x, fmaf(wz.y,h4.y, fmaf(wz.z,h4.z, fmaf(wz.w,h4.w, az[hh]))));
                an[hh] = fmaf(wn.x,h4.x, fmaf(wn.y,h4.y, fmaf(wn.z,h4.z, fmaf(wn.w,h4.w, an[hh]))));
            }
        }
        #pragma unroll
        for (int hh = 0; hh < 4; ++hh) {
            const int row = hb + hh;
            float ir  = fmaf(P.w0i[row      ], x, P.b0i[row      ]);
            float iz  = fmaf(P.w0i[row +  64], x, P.b0i[row +  64]);
            float in_ = fmaf(P.w0i[row + 128], x, P.b0i[row + 128]);
            float r = sigf(ir + ar[hh] + P.b0h[row]);
            float z = sigf(iz + az[hh] + P.b0h[row + 64]);
            float n = tanhfast(in_ + r * (an[hh] + P.b0h[row + 128]));
            float hold = h0[lane * PAD + row];
            hn0[g * 4 + hh] = (1.f - z) * n + z * hold;
        }
    }
    __syncthreads();                      // all reads of old h0 done
    #pragma unroll
    for (int j = 0; j < 8; ++j) h0[lane * PAD + hr0 + j] = hn0[j];
    __syncthreads();                      // h0 now holds y0 = new h0

    // ---------- layer 1 (input = y0 in h0, hidden = h1) ----------
    float hn1[8];
    #pragma unroll
    for (int g = 0; g < 2; ++g) {
        const int hb = hr0 + g * 4;
        float ar[4] = {0.f,0.f,0.f,0.f}, az[4] = {0.f,0.f,0.f,0.f};
        float ai[4] = {0.f,0.f,0.f,0.f}, ah[4] = {0.f,0.f,0.f,0.f};
        for (int kc = 0; kc < 16; ++kc) {        // input pass: wih1 @ y0
            float4 y4 = *(const float4*)&h0[lane * PAD + kc * 4];
            #pragma unroll
            for (int hh = 0; hh < 4; ++hh) {
                const int row = hb + hh;
                float4 wr = *(const float4*)&P.w1i[(row      ) * HD + kc * 4];
                float4 wz = *(const float4*)&P.w1i[(row +  64) * HD + kc * 4];
                float4 wn = *(const float4*)&P.w1i[(row + 128) * HD + kc * 4];
                ar[hh] = fmaf(wr.x,y4.x, fmaf(wr.y,y4.y, fmaf(wr.z,y4.z, fmaf(wr.w,y4.w, ar[hh]))));
                az[hh] = fmaf(wz.x,y4.x, fmaf(wz.y,y4.y, fmaf(wz.z,y4.z, fmaf(wz.w,y4.w, az[hh]))));
                ai[hh] = fmaf(wn.x,y4.x, fmaf(wn.y,y4.y, fmaf(wn.z,y4.z, fmaf(wn.w,y4.w, ai[hh]))));
            }
        }
        for (int kc = 0; kc < 16; ++kc) {        // hidden pass: whh1 @ h1
            float4 h4 = *(const float4*)&h1[lane * PAD + kc * 4];
            #pragma unroll
            for (int hh = 0; hh < 4; ++hh) {
                const int row = hb + hh;
                float4 wr = *(const float4*)&P.w1h[(row      ) * HD + kc * 4];
                float4 wz = *(const float4*)&P.w1h[(row +  64) * HD + kc * 4];
                float4 wn = *(const float4*)&P.w1h[(row + 128) * HD + kc * 4];
                ar[hh] = fmaf(wr.x,h4.x, fmaf(wr.y,h4.y, fmaf(wr.z,h4.z, fmaf(wr.w,h4.w, ar[hh]))));
                az[hh] = fmaf(wz.x,h4.x, fmaf(wz.y,h4.y, fmaf(wz.z,h4.z, fmaf(wz.w,h4.w, az[hh]))));
                ah[hh] = fmaf(wn.x,h4.x, fmaf(wn.y,h4.y, fmaf(wn.z,h4.z, fmaf(wn.w,h4.w, ah[hh]))));
            }
        }
        #pragma unroll
        for (int hh = 0; hh < 4; ++hh) {
            const int row = hb + hh;
            float r = sigf(ar[hh] + P.b1i[row]       + P.b1h[row]);
            float z = sigf(az[hh] + P.b1i[row + 64]  + P.b1h[row + 64]);
            float n = tanhfast(ai[hh] + P.b1i[row + 128] + r * (ah[hh] + P.b1h[row + 128]));
            float hold = h1[lane * PAD + row];
            hn1[g * 4 + hh] = (1.f - z) * n + z * hold;
        }
    }
    __syncthreads();                      // all reads of old h1 / y0 done
    #pragma unroll
    for (int j = 0; j < 8; ++j) h1[lane * PAD + hr0 + j] = hn1[j];
    __syncthreads();                      // h1 now holds y1 = new h1

    // ---------- output head: relu(y1 @ o1w.T + o1b) @ o2w.T + o2b ----------
    float psum = 0.f;
    #pragma unroll
    for (int g = 0; g < 2; ++g) {
        const int hb = hr0 + g * 4;
        float ac[4] = {0.f,0.f,0.f,0.f};
        for (int kc = 0; kc < 16; ++kc) {
            float4 y4 = *(const float4*)&h1[lane * PAD + kc * 4];
            #pragma unroll
            for (int hh = 0; hh < 4; ++hh) {
                float4 w = *(const float4*)&P.o1w[(hb + hh) * HD + kc * 4];
                ac[hh] = fmaf(w.x,y4.x, fmaf(w.y,y4.y, fmaf(w.z,y4.z, fmaf(w.w,y4.w, ac[hh]))));
            }
        }
        #pragma unroll
        for (int hh = 0; hh < 4; ++hh) {
            const int row = hb + hh;
            float v = fmaxf(ac[hh] + P.o1b[row], 0.f);
            psum = fmaf(v, P.o2w[row], psum);
        }
    }
    red[wv * 64 + lane] = psum;
    __syncthreads();
    float tot = P.o2b[0];
    #pragma unroll
    for (int w = 0; w < 8; ++w) tot += red[w * 64 + lane];
    __syncthreads();                      // protect red before next call
    return tot;
}

__global__ __launch_bounds__(512)
void enc_kernel(const float* __restrict__ enc_in, GruP P,
                float* __restrict__ enc_out, float* __restrict__ h0g,
                float* __restrict__ h1g, float* __restrict__ hist)
{
    __shared__ float h0s[64 * PAD];
    __shared__ float h1s[64 * PAD];
    __shared__ float reds[8 * 64];
    const int lane  = threadIdx.x & 63;
    const int wv    = __builtin_amdgcn_readfirstlane(threadIdx.x >> 6);
    const int node0 = blockIdx.x * 64;
    const int node  = node0 + lane;
    const bool valid = node < NN;

    for (int i = threadIdx.x; i < 64 * PAD; i += 512) { h0s[i] = 0.f; h1s[i] = 0.f; }
    __syncthreads();

    for (int t = 0; t < TE; ++t) {
        float x = valid ? enc_in[node * TE + t] : 0.f;
        float y = gru2_step(lane, wv, x, h0s, h1s, reds, P);
        if (wv == 0 && valid) {
            enc_out[node * TE + t] = y;
            if (t == TE - 1) hist[node * HW + 6] = y;   // y_prev init
        }
    }
    // write final hidden states (h0s/h1s hold them; last barrier inside gru2_step)
    for (int i = threadIdx.x; i < 64 * 64; i += 512) {
        int nn = i >> 6, k = i & 63;
        if (node0 + nn < NN) {
            h0g[(size_t)(node0 + nn) * HD + k] = h0s[nn * PAD + k];
            h1g[(size_t)(node0 + nn) * HD + k] = h1s[nn * PAD + k];
        }
    }
    if (wv == 0 && valid) {
        #pragma unroll
        for (int j = 0; j < 6; ++j)
            hist[node * HW + j] = enc_in[node * TE + 42 + j];   // buf6 init
    }
}

__global__ __launch_bounds__(256)
void edge_kernel(int t, const float* __restrict__ hist, const int* __restrict__ eidx,
                 const float* __restrict__ ea,
                 const float* __restrict__ w1, const float* __restrict__ b1,
                 const float* __restrict__ w2, const float* __restrict__ b2,
                 const float* __restrict__ wo, const float* __restrict__ bo,
                 float* __restrict__ m_buf)
{
    const int e = blockIdx.x * 256 + threadIdx.x;
    if (e >= EE) return;
    const int sj = eidx[e];
    const int di = eidx[EE + e];
    const float* pj = &hist[(size_t)sj * HW + t];
    const float* pi = &hist[(size_t)di * HW + t];
    float feat[14];
    #pragma unroll
    for (int c = 0; c < 7; ++c) {
        float xj = pj[c];
        feat[c]     = xj;
        feat[7 + c] = xj - pi[c];
    }
    float m1[64];
    #pragma unroll
    for (int j = 0; j < 64; ++j) {
        float a = b1[j];
        #pragma unroll
        for (int c = 0; c < 14; ++c) a = fmaf(w1[j * 14 + c], feat[c], a);
        m1[j] = fmaxf(a, 0.f);
    }
    float out = bo[0];
    #pragma unroll 4
    for (int r = 0; r < 32; ++r) {
        float a = b2[r];
        #pragma unroll
        for (int k = 0; k < 64; ++k) a = fmaf(w2[r * 64 + k], m1[k], a);
        out = fmaf(wo[r], fmaxf(a, 0.f), out);
    }
    m_buf[e] = out * ea[e];
}

__global__ __launch_bounds__(512)
void dec_node_kernel(int t, GruP P,
                     const float* __restrict__ m_buf, const float* __restrict__ nrm,
                     const float* __restrict__ lin_w, const float* __restrict__ oparam,
                     float* __restrict__ hist, float* __restrict__ h0g,
                     float* __restrict__ h1g, float* __restrict__ dec_out)
{
    __shared__ float h0s[64 * PAD];
    __shared__ float h1s[64 * PAD];
    __shared__ float reds[8 * 64];
    const int lane  = threadIdx.x & 63;
    const int wv    = __builtin_amdgcn_readfirstlane(threadIdx.x >> 6);
    const int node0 = blockIdx.x * 64;
    const int node  = node0 + lane;
    const bool valid = node < NN;

    for (int i = threadIdx.x; i < 64 * 64; i += 512) {
        int nn = i >> 6, k = i & 63;
        float v0 = 0.f, v1 = 0.f;
        if (node0 + nn < NN) {
            v0 = h0g[(size_t)(node0 + nn) * HD + k];
            v1 = h1g[(size_t)(node0 + nn) * HD + k];
        }
        h0s[nn * PAD + k] = v0;
        h1s[nn * PAD + k] = v1;
    }
    __syncthreads();

    float x = valid ? hist[node * HW + t + 6] : 0.f;   // y_prev
    float y = gru2_step(lane, wv, x, h0s, h1s, reds, P);

    if (wv == 0 && valid) {
        float agg = 0.f;
        #pragma unroll
        for (int k = 0; k < DEG; ++k) agg += m_buf[node + k * NN];
        float diff = agg / nrm[node] * lin_w[0];
        float s = sigf(oparam[0]);
        float o = s * y + (1.f - s) * diff;
        dec_out[node * TF + t]   = o;
        hist[node * HW + t + 7]  = o;
    }
    // write back hidden states
    for (int i = threadIdx.x; i < 64 * 64; i += 512) {
        int nn = i >> 6, k = i & 63;
        if (node0 + nn < NN) {
            h0g[(size_t)(node0 + nn) * HD + k] = h0s[nn * PAD + k];
            h1g[(size_t)(node0 + nn) * HD + k] = h1s[nn * PAD + k];
        }
    }
}

__global__ __launch_bounds__(256)
void norm_kernel(const float* __restrict__ ea, float* __restrict__ nrm)
{
    const int n = blockIdx.x * 256 + threadIdx.x;
    if (n >= NN) return;
    float s = 0.f;
    #pragma unroll
    for (int k = 0; k < DEG; ++k) s += ea[n + k * NN];
    nrm[n] = s;
}

extern "C" void kernel_launch(void* const* d_in, const int* in_sizes, int n_in,
                              void* d_out, int out_size, void* d_ws, size_t ws_size,
                              hipStream_t stream)
{
    const float* enc_in = (const float*)d_in[0];
    const float* ea     = (const float*)d_in[1];
    const int*   eidx   = (const int*)d_in[2];
    GruP P;
    P.w0i = (const float*)d_in[3];  P.w0h = (const float*)d_in[4];
    P.b0i = (const float*)d_in[5];  P.b0h = (const float*)d_in[6];
    P.w1i = (const float*)d_in[7];  P.w1h = (const float*)d_in[8];
    P.b1i = (const float*)d_in[9];  P.b1h = (const float*)d_in[10];
    P.o1w = (const float*)d_in[11]; P.o1b = (const float*)d_in[12];
    P.o2w = (const float*)d_in[13]; P.o2b = (const float*)d_in[14];
    const float* gw1  = (const float*)d_in[15];
    const float* gb1  = (const float*)d_in[16];
    const float* gw2  = (const float*)d_in[17];
    const float* gb2  = (const float*)d_in[18];
    const float* gwo  = (const float*)d_in[19];
    const float* gbo  = (const float*)d_in[20];
    const float* glin = (const float*)d_in[21];
    const float* gop  = (const float*)d_in[22];

    float* dec_out = (float*)d_out;                 // [NN][24]
    float* enc_out = dec_out + (size_t)NN * TF;     // [NN][48]

    float* ws    = (float*)d_ws;
    float* h0g   = ws;                              // NN*64
    float* h1g   = h0g + (size_t)NN * HD;           // NN*64
    float* hist  = h1g + (size_t)NN * HD;           // NN*31
    float* m_buf = hist + (size_t)NN * HW;          // EE
    float* nrm   = m_buf + (size_t)EE;              // NN

    const int nblk = (NN + 63) / 64;                // 782

    norm_kernel<<<(NN + 255) / 256, 256, 0, stream>>>(ea, nrm);
    enc_kernel<<<nblk, 512, 0, stream>>>(enc_in, P, enc_out, h0g, h1g, hist);
    for (int t = 0; t < TF; ++t) {
        edge_kernel<<<EE / 256, 256, 0, stream>>>(t, hist, eidx, ea,
                                                  gw1, gb1, gw2, gb2, gwo, gbo, m_buf);
        dec_node_kernel<<<nblk, 512, 0, stream>>>(t, P, m_buf, nrm, glin, gop,
                                                  hist, h0g, h1g, dec_out);
    }
}

// Round 2
// 7122.196 us; speedup vs baseline: 2.9484x; 2.9484x over previous
//
#include <hip/hip_runtime.h>

#define NN 50000
#define TE 48
#define TF 24
#define HD 64
#define DEG 32
#define EE (NN*DEG)
#define HW 31      // hist width: 6 warmup + 1 y_prev + 24 outputs

typedef _Float16 f16;
typedef __attribute__((ext_vector_type(8))) _Float16 f16x8;
typedef __attribute__((ext_vector_type(4))) float f32x4;

// packed weight-fragment offsets (f16 elements)
#define OFF_W0H 0
#define OFF_W1I 12288
#define OFF_W1H 24576
#define OFF_O1W 36864
#define WFRAG_ELEMS 40960

__device__ __forceinline__ float sigf(float x) { return 1.f / (1.f + __expf(-x)); }
__device__ __forceinline__ float tanhfast(float x) {
    float t = __expf(-2.f * fabsf(x));   // t in (0,1], no overflow
    float r = (1.f - t) / (1.f + t);
    return x < 0.f ? -r : r;
}

// -------- per-lane constants for the MFMA GRU step --------
struct LaneC {
    float w0ir[2], w0iz[2], w0in[2];
    float b0rzr[2], b0rzz[2], b0ni[2], b0nh[2];
    float b1rzr[2], b1rzz[2], b1ni[2], b1nh[2];
    float o1bc[2], o2wc[2];
    int wa[2][4];   // LDS elem addr (swizzled) for this lane's C-tile elements
    int ra[2];      // LDS elem addr (swizzled) for A-frag k-step s
    int xb;         // xs base index for this lane's 4 node rows
};

__device__ __forceinline__ void make_lane(LaneC& C, int l, int mi, int nj,
    const float* w0i, const float* b0i, const float* b0h,
    const float* b1i, const float* b1h, const float* o1b, const float* o2w)
{
    const int jc = l & 15, ig = l >> 4;
    #pragma unroll
    for (int c = 0; c < 2; ++c) {
        const int hc = (nj * 2 + c) * 16 + jc;
        C.w0ir[c] = w0i[hc]; C.w0iz[c] = w0i[64 + hc]; C.w0in[c] = w0i[128 + hc];
        C.b0rzr[c] = b0i[hc] + b0h[hc];
        C.b0rzz[c] = b0i[64 + hc] + b0h[64 + hc];
        C.b0ni[c] = b0i[128 + hc]; C.b0nh[c] = b0h[128 + hc];
        C.b1rzr[c] = b1i[hc] + b1h[hc];
        C.b1rzz[c] = b1i[64 + hc] + b1h[64 + hc];
        C.b1ni[c] = b1i[128 + hc]; C.b1nh[c] = b1h[128 + hc];
        C.o1bc[c] = o1b[hc]; C.o2wc[c] = o2w[hc];
        const int chunk = hc >> 3;
        #pragma unroll
        for (int r = 0; r < 4; ++r) {
            const int row = mi * 16 + ig * 4 + r;
            C.wa[c][r] = row * 64 + ((chunk ^ (row & 7)) << 3) + (hc & 7);
        }
    }
    const int rowa = mi * 16 + jc;
    #pragma unroll
    for (int s = 0; s < 2; ++s)
        C.ra[s] = rowa * 64 + (((s * 4 + ig) ^ (rowa & 7)) << 3);
    C.xb = mi * 16 + ig * 4;
}

__device__ __forceinline__ f32x4 mfma16(f16x8 a, const f16* p, f32x4 c) {
    return __builtin_amdgcn_mfma_f32_16x16x32_f16(a, *(const f16x8*)p, c, 0, 0, 0);
}

// One 2-layer GRU step + output head for 64 nodes via MFMA.
// Ends with barrier E; caller reads red[] afterwards.
template<bool ENC>
__device__ __forceinline__ void gru_step(
    int tid, int l, int mi, int nj,
    f16* h0s, f16* h1s, float* xs, float* red,
    const f16* __restrict__ wf, const LaneC& C,
    float (&h0o)[2][4], float (&h1o)[2][4],
    const float* __restrict__ enc_in, int t, int node0)
{
    const f32x4 z4 = {0.f, 0.f, 0.f, 0.f};
    const int lb = l << 3;   // lane*8 f16 into frag

    // ---- stage 1: read x and A-frags of h0_old ----
    float xv[4];
    #pragma unroll
    for (int r = 0; r < 4; ++r) xv[r] = xs[C.xb + r];
    f16x8 a0[2];
    #pragma unroll
    for (int s = 0; s < 2; ++s) a0[s] = *(const f16x8*)&h0s[C.ra[s]];

    // ---- layer 0 hidden GEMM: 12 MFMAs ----
    f32x4 aR[2], aZ[2], aN[2];
    #pragma unroll
    for (int c = 0; c < 2; ++c) {
        const int ct = nj * 2 + c;
        aR[c] = z4; aZ[c] = z4; aN[c] = z4;
        #pragma unroll
        for (int s = 0; s < 2; ++s) {
            aR[c] = mfma16(a0[s], wf + OFF_W0H + (((0 + ct) * 2 + s) << 9) + lb, aR[c]);
            aZ[c] = mfma16(a0[s], wf + OFF_W0H + (((4 + ct) * 2 + s) << 9) + lb, aZ[c]);
            aN[c] = mfma16(a0[s], wf + OFF_W0H + (((8 + ct) * 2 + s) << 9) + lb, aN[c]);
        }
    }
    // ---- layer 0 gates ----
    float hn0[2][4];
    #pragma unroll
    for (int c = 0; c < 2; ++c)
        #pragma unroll
        for (int r = 0; r < 4; ++r) {
            float rg = sigf(aR[c][r] + xv[r] * C.w0ir[c] + C.b0rzr[c]);
            float zg = sigf(aZ[c][r] + xv[r] * C.w0iz[c] + C.b0rzz[c]);
            float ng = tanhfast(xv[r] * C.w0in[c] + C.b0ni[c] + rg * (aN[c][r] + C.b0nh[c]));
            float h2 = (1.f - zg) * ng + zg * h0o[c][r];
            h0o[c][r] = h2; hn0[c][r] = h2;
        }
    __syncthreads();                                   // A: all reads of old h0 done
    #pragma unroll
    for (int c = 0; c < 2; ++c)
        #pragma unroll
        for (int r = 0; r < 4; ++r) h0s[C.wa[c][r]] = (f16)hn0[c][r];
    if (ENC) {
        if (tid < 64 && t + 1 < TE && node0 + tid < NN)
            xs[tid] = enc_in[(size_t)(node0 + tid) * TE + t + 1];
    }
    __syncthreads();                                   // B: h0s now y0

    // ---- layer 1: two GEMMs, 24 MFMAs ----
    f16x8 ay[2], ah[2];
    #pragma unroll
    for (int s = 0; s < 2; ++s) {
        ay[s] = *(const f16x8*)&h0s[C.ra[s]];
        ah[s] = *(const f16x8*)&h1s[C.ra[s]];
    }
    f32x4 bR[2], bZ[2], bNi[2], bNh[2];
    #pragma unroll
    for (int c = 0; c < 2; ++c) {
        const int ct = nj * 2 + c;
        bR[c] = z4; bZ[c] = z4; bNi[c] = z4; bNh[c] = z4;
        #pragma unroll
        for (int s = 0; s < 2; ++s) {
            bR[c]  = mfma16(ay[s], wf + OFF_W1I + (((0 + ct) * 2 + s) << 9) + lb, bR[c]);
            bR[c]  = mfma16(ah[s], wf + OFF_W1H + (((0 + ct) * 2 + s) << 9) + lb, bR[c]);
            bZ[c]  = mfma16(ay[s], wf + OFF_W1I + (((4 + ct) * 2 + s) << 9) + lb, bZ[c]);
            bZ[c]  = mfma16(ah[s], wf + OFF_W1H + (((4 + ct) * 2 + s) << 9) + lb, bZ[c]);
            bNi[c] = mfma16(ay[s], wf + OFF_W1I + (((8 + ct) * 2 + s) << 9) + lb, bNi[c]);
            bNh[c] = mfma16(ah[s], wf + OFF_W1H + (((8 + ct) * 2 + s) << 9) + lb, bNh[c]);
        }
    }
    float hn1[2][4];
    #pragma unroll
    for (int c = 0; c < 2; ++c)
        #pragma unroll
        for (int r = 0; r < 4; ++r) {
            float rg = sigf(bR[c][r] + C.b1rzr[c]);
            float zg = sigf(bZ[c][r] + C.b1rzz[c]);
            float ng = tanhfast(bNi[c][r] + C.b1ni[c] + rg * (bNh[c][r] + C.b1nh[c]));
            float h2 = (1.f - zg) * ng + zg * h1o[c][r];
            h1o[c][r] = h2; hn1[c][r] = h2;
        }
    __syncthreads();                                   // C: all reads of old h1 done
    #pragma unroll
    for (int c = 0; c < 2; ++c)
        #pragma unroll
        for (int r = 0; r < 4; ++r) h1s[C.wa[c][r]] = (f16)hn1[c][r];
    __syncthreads();                                   // D: h1s now y1

    // ---- output head: relu(y1@o1w.T+o1b)@o2w.T ----
    f16x8 a1[2];
    #pragma unroll
    for (int s = 0; s < 2; ++s) a1[s] = *(const f16x8*)&h1s[C.ra[s]];
    float ps[4] = {0.f, 0.f, 0.f, 0.f};
    #pragma unroll
    for (int c = 0; c < 2; ++c) {
        const int ct = nj * 2 + c;
        f32x4 aH = z4;
        #pragma unroll
        for (int s = 0; s < 2; ++s)
            aH = mfma16(a1[s], wf + OFF_O1W + ((ct * 2 + s) << 9) + lb, aH);
        #pragma unroll
        for (int r = 0; r < 4; ++r)
            ps[r] += fmaxf(aH[r] + C.o1bc[c], 0.f) * C.o2wc[c];
    }
    #pragma unroll
    for (int m = 1; m < 16; m <<= 1)
        #pragma unroll
        for (int r = 0; r < 4; ++r) ps[r] += __shfl_xor(ps[r], m, 64);
    if ((l & 15) == 0) {
        const int ig = l >> 4;
        #pragma unroll
        for (int r = 0; r < 4; ++r)
            red[(mi * 2 + nj) * 16 + ig * 4 + r] = ps[r];
    }
    __syncthreads();                                   // E: red ready
}

// -------- weight fragment packing (once per launch) --------
__global__ __launch_bounds__(256)
void pack_weights(const float* __restrict__ w0h, const float* __restrict__ w1i,
                  const float* __restrict__ w1h, const float* __restrict__ o1w,
                  f16* __restrict__ wf)
{
    const int t = blockIdx.x * 256 + threadIdx.x;
    if (t >= 80 * 64) return;
    const int f = t >> 6, l = t & 63;
    const float* src; int nt, s;
    if (f < 24)      { src = w0h; nt = f >> 1;        s = f & 1; }
    else if (f < 48) { src = w1i; nt = (f - 24) >> 1; s = f & 1; }
    else if (f < 72) { src = w1h; nt = (f - 48) >> 1; s = f & 1; }
    else             { src = o1w; nt = (f - 72) >> 1; s = f & 1; }
    const int row = nt * 16 + (l & 15);
    const int k0  = s * 32 + (l >> 4) * 8;
    #pragma unroll
    for (int e = 0; e < 8; ++e)
        wf[f * 512 + l * 8 + e] = (f16)src[row * 64 + k0 + e];
}

// -------- encoder: 48 GRU steps per block of 64 nodes --------
__global__ __launch_bounds__(512)
void enc_kernel(const float* __restrict__ enc_in,
    const float* __restrict__ w0i, const float* __restrict__ b0i, const float* __restrict__ b0h,
    const float* __restrict__ b1i, const float* __restrict__ b1h,
    const float* __restrict__ o1b, const float* __restrict__ o2w, const float* __restrict__ o2b,
    const f16* __restrict__ wf,
    float* __restrict__ enc_out, f16* __restrict__ h0g, f16* __restrict__ h1g,
    float* __restrict__ hist)
{
    __shared__ f16 h0s[4096];
    __shared__ f16 h1s[4096];
    __shared__ float xs[64];
    __shared__ float red[128];
    const int tid = threadIdx.x;
    const int l = tid & 63;
    const int w = __builtin_amdgcn_readfirstlane(tid >> 6);
    const int mi = w >> 1, nj = w & 1;
    const int node0 = blockIdx.x * 64;

    LaneC C; make_lane(C, l, mi, nj, w0i, b0i, b0h, b1i, b1h, o1b, o2w);
    float h0o[2][4] = {}, h1o[2][4] = {};
    for (int i = tid; i < 4096; i += 512) { h0s[i] = (f16)0.f; h1s[i] = (f16)0.f; }
    if (tid < 64) xs[tid] = (node0 + tid < NN) ? enc_in[(size_t)(node0 + tid) * TE] : 0.f;
    __syncthreads();

    const float o2b0 = o2b[0];
    for (int t = 0; t < TE; ++t) {
        gru_step<true>(tid, l, mi, nj, h0s, h1s, xs, red, wf, C, h0o, h1o, enc_in, t, node0);
        if (tid < 64 && node0 + tid < NN) {
            float y = red[(tid >> 4) * 32 + (tid & 15)]
                    + red[(tid >> 4) * 32 + 16 + (tid & 15)] + o2b0;
            enc_out[(size_t)(node0 + tid) * TE + t] = y;
            if (t == TE - 1) hist[(size_t)(node0 + tid) * HW + 6] = y;
        }
    }
    // store hidden states (f16, linear layout)
    {
        const int row = tid >> 3, chunk = tid & 7;
        if (node0 + row < NN) {
            const int src = row * 64 + ((chunk ^ (row & 7)) << 3);
            *(f16x8*)&h0g[(size_t)(node0 + row) * 64 + chunk * 8] = *(const f16x8*)&h0s[src];
            *(f16x8*)&h1g[(size_t)(node0 + row) * 64 + chunk * 8] = *(const f16x8*)&h1s[src];
        }
    }
    if (tid < 64 && node0 + tid < NN) {
        #pragma unroll
        for (int j = 0; j < 6; ++j)
            hist[(size_t)(node0 + tid) * HW + j] = enc_in[(size_t)(node0 + tid) * TE + 42 + j];
    }
}

// -------- decoder node step --------
__global__ __launch_bounds__(512)
void dec_node_kernel(int t,
    const float* __restrict__ w0i, const float* __restrict__ b0i, const float* __restrict__ b0h,
    const float* __restrict__ b1i, const float* __restrict__ b1h,
    const float* __restrict__ o1b, const float* __restrict__ o2w, const float* __restrict__ o2b,
    const f16* __restrict__ wf,
    const float* __restrict__ m_buf, const float* __restrict__ nrm,
    const float* __restrict__ lin_w, const float* __restrict__ oparam,
    float* __restrict__ hist, f16* __restrict__ h0g, f16* __restrict__ h1g,
    float* __restrict__ dec_out)
{
    __shared__ f16 h0s[4096];
    __shared__ f16 h1s[4096];
    __shared__ float xs[64];
    __shared__ float red[128];
    const int tid = threadIdx.x;
    const int l = tid & 63;
    const int w = __builtin_amdgcn_readfirstlane(tid >> 6);
    const int mi = w >> 1, nj = w & 1;
    const int node0 = blockIdx.x * 64;

    LaneC C; make_lane(C, l, mi, nj, w0i, b0i, b0h, b1i, b1h, o1b, o2w);

    const int row = tid >> 3, chunk = tid & 7;
    const int del = row * 64 + ((chunk ^ (row & 7)) << 3);
    if (node0 + row < NN) {
        *(f16x8*)&h0s[del] = *(const f16x8*)&h0g[(size_t)(node0 + row) * 64 + chunk * 8];
        *(f16x8*)&h1s[del] = *(const f16x8*)&h1g[(size_t)(node0 + row) * 64 + chunk * 8];
    } else {
        f16x8 z = {};
        *(f16x8*)&h0s[del] = z;
        *(f16x8*)&h1s[del] = z;
    }
    if (tid < 64) xs[tid] = (node0 + tid < NN) ? hist[(size_t)(node0 + tid) * HW + t + 6] : 0.f;
    __syncthreads();

    float h0o[2][4], h1o[2][4];
    #pragma unroll
    for (int c = 0; c < 2; ++c)
        #pragma unroll
        for (int r = 0; r < 4; ++r) {
            h0o[c][r] = (float)h0s[C.wa[c][r]];
            h1o[c][r] = (float)h1s[C.wa[c][r]];
        }

    gru_step<false>(tid, l, mi, nj, h0s, h1s, xs, red, wf, C, h0o, h1o, nullptr, t, node0);

    if (tid < 64 && node0 + tid < NN) {
        const int node = node0 + tid;
        float y = red[(tid >> 4) * 32 + (tid & 15)]
                + red[(tid >> 4) * 32 + 16 + (tid & 15)] + o2b[0];
        float agg = 0.f;
        #pragma unroll
        for (int k = 0; k < DEG; ++k) agg += m_buf[node + k * NN];
        float diff = agg / nrm[node] * lin_w[0];
        float s = sigf(oparam[0]);
        float o = s * y + (1.f - s) * diff;
        dec_out[(size_t)node * TF + t] = o;
        hist[(size_t)node * HW + t + 7] = o;
    }
    if (node0 + row < NN) {
        *(f16x8*)&h0g[(size_t)(node0 + row) * 64 + chunk * 8] = *(const f16x8*)&h0s[del];
        *(f16x8*)&h1g[(size_t)(node0 + row) * 64 + chunk * 8] = *(const f16x8*)&h1s[del];
    }
}

// -------- GNN edge MLP --------
__global__ __launch_bounds__(256)
void edge_kernel(int t, const float* __restrict__ hist, const int* __restrict__ eidx,
                 const float* __restrict__ ea,
                 const float* __restrict__ w1, const float* __restrict__ b1,
                 const float* __restrict__ w2, const float* __restrict__ b2,
                 const float* __restrict__ wo, const float* __restrict__ bo,
                 float* __restrict__ m_buf)
{
    __shared__ float w1s[896], w2s[2048], b1s[64], b2s[32], wos[32];
    const int tid = threadIdx.x;
    for (int i = tid; i < 896; i += 256) w1s[i] = w1[i];
    for (int i = tid; i < 2048; i += 256) w2s[i] = w2[i];
    if (tid < 64) b1s[tid] = b1[tid];
    if (tid < 32) { b2s[tid] = b2[tid]; wos[tid] = wo[tid]; }
    __syncthreads();

    const int e = blockIdx.x * 256 + tid;
    const int sj = eidx[e];
    const int di = eidx[EE + e];
    const float* pj = &hist[(size_t)sj * HW + t];
    const float* pi = &hist[(size_t)di * HW + t];
    float feat[14];
    #pragma unroll
    for (int c = 0; c < 7; ++c) {
        float xj = pj[c];
        feat[c]     = xj;
        feat[7 + c] = xj - pi[c];
    }
    float acc[32];
    #pragma unroll
    for (int r = 0; r < 32; ++r) acc[r] = b2s[r];
    #pragma unroll 4
    for (int j = 0; j < 64; ++j) {
        float m = b1s[j];
        #pragma unroll
        for (int c = 0; c < 14; ++c) m = fmaf(w1s[j * 14 + c], feat[c], m);
        m = fmaxf(m, 0.f);
        #pragma unroll
        for (int r = 0; r < 32; ++r) acc[r] = fmaf(w2s[r * 64 + j], m, acc[r]);
    }
    float out = bo[0];
    #pragma unroll
    for (int r = 0; r < 32; ++r) out = fmaf(wos[r], fmaxf(acc[r], 0.f), out);
    m_buf[e] = out * ea[e];
}

__global__ __launch_bounds__(256)
void norm_kernel(const float* __restrict__ ea, float* __restrict__ nrm)
{
    const int n = blockIdx.x * 256 + threadIdx.x;
    if (n >= NN) return;
    float s = 0.f;
    #pragma unroll
    for (int k = 0; k < DEG; ++k) s += ea[n + k * NN];
    nrm[n] = s;
}

extern "C" void kernel_launch(void* const* d_in, const int* in_sizes, int n_in,
                              void* d_out, int out_size, void* d_ws, size_t ws_size,
                              hipStream_t stream)
{
    const float* enc_in = (const float*)d_in[0];
    const float* ea     = (const float*)d_in[1];
    const int*   eidx   = (const int*)d_in[2];
    const float* w0i = (const float*)d_in[3];
    const float* w0h = (const float*)d_in[4];
    const float* b0i = (const float*)d_in[5];
    const float* b0h = (const float*)d_in[6];
    const float* w1i = (const float*)d_in[7];
    const float* w1h = (const float*)d_in[8];
    const float* b1i = (const float*)d_in[9];
    const float* b1h = (const float*)d_in[10];
    const float* o1w = (const float*)d_in[11];
    const float* o1b = (const float*)d_in[12];
    const float* o2w = (const float*)d_in[13];
    const float* o2b = (const float*)d_in[14];
    const float* gw1  = (const float*)d_in[15];
    const float* gb1  = (const float*)d_in[16];
    const float* gw2  = (const float*)d_in[17];
    const float* gb2  = (const float*)d_in[18];
    const float* gwo  = (const float*)d_in[19];
    const float* gbo  = (const float*)d_in[20];
    const float* glin = (const float*)d_in[21];
    const float* gop  = (const float*)d_in[22];

    float* dec_out = (float*)d_out;                 // [NN][24]
    float* enc_out = dec_out + (size_t)NN * TF;     // [NN][48]

    // workspace layout (all 16B aligned)
    f16*   h0g   = (f16*)d_ws;                      // NN*64 f16
    f16*   h1g   = h0g + (size_t)NN * HD;           // NN*64 f16
    float* hist  = (float*)(h1g + (size_t)NN * HD); // NN*31 f32
    float* m_buf = hist + (size_t)NN * HW;          // EE f32
    float* nrm   = m_buf + (size_t)EE;              // NN f32
    f16*   wfrag = (f16*)(nrm + NN);                // 40960 f16

    const int nblk = (NN + 63) / 64;                // 782

    pack_weights<<<20, 256, 0, stream>>>(w0h, w1i, w1h, o1w, wfrag);
    norm_kernel<<<(NN + 255) / 256, 256, 0, stream>>>(ea, nrm);
    enc_kernel<<<nblk, 512, 0, stream>>>(enc_in, w0i, b0i, b0h, b1i, b1h,
                                         o1b, o2w, o2b, wfrag,
                                         enc_out, h0g, h1g, hist);
    for (int t = 0; t < TF; ++t) {
        edge_kernel<<<EE / 256, 256, 0, stream>>>(t, hist, eidx, ea,
                                                  gw1, gb1, gw2, gb2, gwo, gbo, m_buf);
        dec_node_kernel<<<nblk, 512, 0, stream>>>(t, w0i, b0i, b0h, b1i, b1h,
                                                  o1b, o2w, o2b, wfrag,
                                                  m_buf, nrm, glin, gop,
                                                  hist, h0g, h1g, dec_out);
    }
}

// Round 3
// 4012.912 us; speedup vs baseline: 5.2329x; 1.7748x over previous
//
#include <hip/hip_runtime.h>

#define NN 50000
#define TE 48
#define TF 24
#define HD 64
#define DEG 32
#define EE (NN*DEG)
#define HW 31      // hist width: 6 warmup + 1 y_prev + 24 outputs

typedef _Float16 f16;
typedef __attribute__((ext_vector_type(8))) _Float16 f16x8;
typedef __attribute__((ext_vector_type(4))) float f32x4;

// packed weight-fragment offsets (f16 elements)
#define OFF_W0H 0
#define OFF_W1I 12288
#define OFF_W1H 24576
#define OFF_O1W 36864
#define OFF_W2  40960
#define NFRAG 84   // 80 GRU frags + 4 w2 frags

__device__ __forceinline__ float sigf(float x) { return 1.f / (1.f + __expf(-x)); }
__device__ __forceinline__ float tanhfast(float x) {
    float t = __expf(-2.f * fabsf(x));   // t in (0,1], no overflow
    float r = (1.f - t) / (1.f + t);
    return x < 0.f ? -r : r;
}

// -------- per-lane constants for the MFMA GRU step --------
struct LaneC {
    float w0ir[2], w0iz[2], w0in[2];
    float b0rzr[2], b0rzz[2], b0ni[2], b0nh[2];
    float b1rzr[2], b1rzz[2], b1ni[2], b1nh[2];
    float o1bc[2], o2wc[2];
    int wa[2][4];
    int ra[2];
    int xb;
};

__device__ __forceinline__ void make_lane(LaneC& C, int l, int mi, int nj,
    const float* w0i, const float* b0i, const float* b0h,
    const float* b1i, const float* b1h, const float* o1b, const float* o2w)
{
    const int jc = l & 15, ig = l >> 4;
    #pragma unroll
    for (int c = 0; c < 2; ++c) {
        const int hc = (nj * 2 + c) * 16 + jc;
        C.w0ir[c] = w0i[hc]; C.w0iz[c] = w0i[64 + hc]; C.w0in[c] = w0i[128 + hc];
        C.b0rzr[c] = b0i[hc] + b0h[hc];
        C.b0rzz[c] = b0i[64 + hc] + b0h[64 + hc];
        C.b0ni[c] = b0i[128 + hc]; C.b0nh[c] = b0h[128 + hc];
        C.b1rzr[c] = b1i[hc] + b1h[hc];
        C.b1rzz[c] = b1i[64 + hc] + b1h[64 + hc];
        C.b1ni[c] = b1i[128 + hc]; C.b1nh[c] = b1h[128 + hc];
        C.o1bc[c] = o1b[hc]; C.o2wc[c] = o2w[hc];
        const int chunk = hc >> 3;
        #pragma unroll
        for (int r = 0; r < 4; ++r) {
            const int row = mi * 16 + ig * 4 + r;
            C.wa[c][r] = row * 64 + ((chunk ^ (row & 7)) << 3) + (hc & 7);
        }
    }
    const int rowa = mi * 16 + jc;
    #pragma unroll
    for (int s = 0; s < 2; ++s)
        C.ra[s] = rowa * 64 + (((s * 4 + ig) ^ (rowa & 7)) << 3);
    C.xb = mi * 16 + ig * 4;
}

__device__ __forceinline__ f32x4 mfma16(f16x8 a, const f16* p, f32x4 c) {
    return __builtin_amdgcn_mfma_f32_16x16x32_f16(a, *(const f16x8*)p, c, 0, 0, 0);
}

template<bool ENC>
__device__ __forceinline__ void gru_step(
    int tid, int l, int mi, int nj,
    f16* h0s, f16* h1s, float* xs, float* red,
    const f16* __restrict__ wf, const LaneC& C,
    float (&h0o)[2][4], float (&h1o)[2][4],
    const float* __restrict__ enc_in, int t, int node0)
{
    const f32x4 z4 = {0.f, 0.f, 0.f, 0.f};
    const int lb = l << 3;

    float xv[4];
    #pragma unroll
    for (int r = 0; r < 4; ++r) xv[r] = xs[C.xb + r];
    f16x8 a0[2];
    #pragma unroll
    for (int s = 0; s < 2; ++s) a0[s] = *(const f16x8*)&h0s[C.ra[s]];

    f32x4 aR[2], aZ[2], aN[2];
    #pragma unroll
    for (int c = 0; c < 2; ++c) {
        const int ct = nj * 2 + c;
        aR[c] = z4; aZ[c] = z4; aN[c] = z4;
        #pragma unroll
        for (int s = 0; s < 2; ++s) {
            aR[c] = mfma16(a0[s], wf + OFF_W0H + (((0 + ct) * 2 + s) << 9) + lb, aR[c]);
            aZ[c] = mfma16(a0[s], wf + OFF_W0H + (((4 + ct) * 2 + s) << 9) + lb, aZ[c]);
            aN[c] = mfma16(a0[s], wf + OFF_W0H + (((8 + ct) * 2 + s) << 9) + lb, aN[c]);
        }
    }
    float hn0[2][4];
    #pragma unroll
    for (int c = 0; c < 2; ++c)
        #pragma unroll
        for (int r = 0; r < 4; ++r) {
            float rg = sigf(aR[c][r] + xv[r] * C.w0ir[c] + C.b0rzr[c]);
            float zg = sigf(aZ[c][r] + xv[r] * C.w0iz[c] + C.b0rzz[c]);
            float ng = tanhfast(xv[r] * C.w0in[c] + C.b0ni[c] + rg * (aN[c][r] + C.b0nh[c]));
            float h2 = (1.f - zg) * ng + zg * h0o[c][r];
            h0o[c][r] = h2; hn0[c][r] = h2;
        }
    __syncthreads();
    #pragma unroll
    for (int c = 0; c < 2; ++c)
        #pragma unroll
        for (int r = 0; r < 4; ++r) h0s[C.wa[c][r]] = (f16)hn0[c][r];
    if (ENC) {
        if (tid < 64 && t + 1 < TE && node0 + tid < NN)
            xs[tid] = enc_in[(size_t)(node0 + tid) * TE + t + 1];
    }
    __syncthreads();

    f16x8 ay[2], ah[2];
    #pragma unroll
    for (int s = 0; s < 2; ++s) {
        ay[s] = *(const f16x8*)&h0s[C.ra[s]];
        ah[s] = *(const f16x8*)&h1s[C.ra[s]];
    }
    f32x4 bR[2], bZ[2], bNi[2], bNh[2];
    #pragma unroll
    for (int c = 0; c < 2; ++c) {
        const int ct = nj * 2 + c;
        bR[c] = z4; bZ[c] = z4; bNi[c] = z4; bNh[c] = z4;
        #pragma unroll
        for (int s = 0; s < 2; ++s) {
            bR[c]  = mfma16(ay[s], wf + OFF_W1I + (((0 + ct) * 2 + s) << 9) + lb, bR[c]);
            bR[c]  = mfma16(ah[s], wf + OFF_W1H + (((0 + ct) * 2 + s) << 9) + lb, bR[c]);
            bZ[c]  = mfma16(ay[s], wf + OFF_W1I + (((4 + ct) * 2 + s) << 9) + lb, bZ[c]);
            bZ[c]  = mfma16(ah[s], wf + OFF_W1H + (((4 + ct) * 2 + s) << 9) + lb, bZ[c]);
            bNi[c] = mfma16(ay[s], wf + OFF_W1I + (((8 + ct) * 2 + s) << 9) + lb, bNi[c]);
            bNh[c] = mfma16(ah[s], wf + OFF_W1H + (((8 + ct) * 2 + s) << 9) + lb, bNh[c]);
        }
    }
    float hn1[2][4];
    #pragma unroll
    for (int c = 0; c < 2; ++c)
        #pragma unroll
        for (int r = 0; r < 4; ++r) {
            float rg = sigf(bR[c][r] + C.b1rzr[c]);
            float zg = sigf(bZ[c][r] + C.b1rzz[c]);
            float ng = tanhfast(bNi[c][r] + C.b1ni[c] + rg * (bNh[c][r] + C.b1nh[c]));
            float h2 = (1.f - zg) * ng + zg * h1o[c][r];
            h1o[c][r] = h2; hn1[c][r] = h2;
        }
    __syncthreads();
    #pragma unroll
    for (int c = 0; c < 2; ++c)
        #pragma unroll
        for (int r = 0; r < 4; ++r) h1s[C.wa[c][r]] = (f16)hn1[c][r];
    __syncthreads();

    f16x8 a1[2];
    #pragma unroll
    for (int s = 0; s < 2; ++s) a1[s] = *(const f16x8*)&h1s[C.ra[s]];
    float ps[4] = {0.f, 0.f, 0.f, 0.f};
    #pragma unroll
    for (int c = 0; c < 2; ++c) {
        const int ct = nj * 2 + c;
        f32x4 aH = z4;
        #pragma unroll
        for (int s = 0; s < 2; ++s)
            aH = mfma16(a1[s], wf + OFF_O1W + ((ct * 2 + s) << 9) + lb, aH);
        #pragma unroll
        for (int r = 0; r < 4; ++r)
            ps[r] += fmaxf(aH[r] + C.o1bc[c], 0.f) * C.o2wc[c];
    }
    #pragma unroll
    for (int m = 1; m < 16; m <<= 1)
        #pragma unroll
        for (int r = 0; r < 4; ++r) ps[r] += __shfl_xor(ps[r], m, 64);
    if ((l & 15) == 0) {
        const int ig = l >> 4;
        #pragma unroll
        for (int r = 0; r < 4; ++r)
            red[(mi * 2 + nj) * 16 + ig * 4 + r] = ps[r];
    }
    __syncthreads();
}

__global__ __launch_bounds__(256)
void pack_weights(const float* __restrict__ w0h, const float* __restrict__ w1i,
                  const float* __restrict__ w1h, const float* __restrict__ o1w,
                  const float* __restrict__ w2,
                  f16* __restrict__ wf)
{
    const int t = blockIdx.x * 256 + threadIdx.x;
    if (t >= NFRAG * 64) return;
    const int f = t >> 6, l = t & 63;
    const float* src; int nt, s;
    if (f < 24)      { src = w0h; nt = f >> 1;        s = f & 1; }
    else if (f < 48) { src = w1i; nt = (f - 24) >> 1; s = f & 1; }
    else if (f < 72) { src = w1h; nt = (f - 48) >> 1; s = f & 1; }
    else if (f < 80) { src = o1w; nt = (f - 72) >> 1; s = f & 1; }
    else             { src = w2;  nt = (f - 80) >> 1; s = f & 1; }
    const int row = nt * 16 + (l & 15);
    const int k0  = s * 32 + (l >> 4) * 8;
    #pragma unroll
    for (int e = 0; e < 8; ++e)
        wf[f * 512 + l * 8 + e] = (f16)src[row * 64 + k0 + e];
}

__global__ __launch_bounds__(512)
void enc_kernel(const float* __restrict__ enc_in,
    const float* __restrict__ w0i, const float* __restrict__ b0i, const float* __restrict__ b0h,
    const float* __restrict__ b1i, const float* __restrict__ b1h,
    const float* __restrict__ o1b, const float* __restrict__ o2w, const float* __restrict__ o2b,
    const f16* __restrict__ wf,
    float* __restrict__ enc_out, f16* __restrict__ h0g, f16* __restrict__ h1g,
    float* __restrict__ hist)
{
    __shared__ f16 h0s[4096];
    __shared__ f16 h1s[4096];
    __shared__ float xs[64];
    __shared__ float red[128];
    const int tid = threadIdx.x;
    const int l = tid & 63;
    const int w = __builtin_amdgcn_readfirstlane(tid >> 6);
    const int mi = w >> 1, nj = w & 1;
    const int node0 = blockIdx.x * 64;

    LaneC C; make_lane(C, l, mi, nj, w0i, b0i, b0h, b1i, b1h, o1b, o2w);
    float h0o[2][4] = {}, h1o[2][4] = {};
    for (int i = tid; i < 4096; i += 512) { h0s[i] = (f16)0.f; h1s[i] = (f16)0.f; }
    if (tid < 64) xs[tid] = (node0 + tid < NN) ? enc_in[(size_t)(node0 + tid) * TE] : 0.f;
    __syncthreads();

    const float o2b0 = o2b[0];
    for (int t = 0; t < TE; ++t) {
        gru_step<true>(tid, l, mi, nj, h0s, h1s, xs, red, wf, C, h0o, h1o, enc_in, t, node0);
        if (tid < 64 && node0 + tid < NN) {
            float y = red[(tid >> 4) * 32 + (tid & 15)]
                    + red[(tid >> 4) * 32 + 16 + (tid & 15)] + o2b0;
            enc_out[(size_t)(node0 + tid) * TE + t] = y;
            if (t == TE - 1) hist[(size_t)(node0 + tid) * HW + 6] = y;
        }
    }
    {
        const int row = tid >> 3, chunk = tid & 7;
        if (node0 + row < NN) {
            const int src = row * 64 + ((chunk ^ (row & 7)) << 3);
            *(f16x8*)&h0g[(size_t)(node0 + row) * 64 + chunk * 8] = *(const f16x8*)&h0s[src];
            *(f16x8*)&h1g[(size_t)(node0 + row) * 64 + chunk * 8] = *(const f16x8*)&h1s[src];
        }
    }
    if (tid < 64 && node0 + tid < NN) {
        #pragma unroll
        for (int j = 0; j < 6; ++j)
            hist[(size_t)(node0 + tid) * HW + j] = enc_in[(size_t)(node0 + tid) * TE + 42 + j];
    }
}

__global__ __launch_bounds__(512)
void dec_node_kernel(int t,
    const float* __restrict__ w0i, const float* __restrict__ b0i, const float* __restrict__ b0h,
    const float* __restrict__ b1i, const float* __restrict__ b1h,
    const float* __restrict__ o1b, const float* __restrict__ o2w, const float* __restrict__ o2b,
    const f16* __restrict__ wf,
    const float* __restrict__ m_buf, const float* __restrict__ nrm,
    const float* __restrict__ lin_w, const float* __restrict__ oparam,
    float* __restrict__ hist, f16* __restrict__ h0g, f16* __restrict__ h1g,
    float* __restrict__ dec_out)
{
    __shared__ f16 h0s[4096];
    __shared__ f16 h1s[4096];
    __shared__ float xs[64];
    __shared__ float red[128];
    const int tid = threadIdx.x;
    const int l = tid & 63;
    const int w = __builtin_amdgcn_readfirstlane(tid >> 6);
    const int mi = w >> 1, nj = w & 1;
    const int node0 = blockIdx.x * 64;

    LaneC C; make_lane(C, l, mi, nj, w0i, b0i, b0h, b1i, b1h, o1b, o2w);

    const int row = tid >> 3, chunk = tid & 7;
    const int del = row * 64 + ((chunk ^ (row & 7)) << 3);
    if (node0 + row < NN) {
        *(f16x8*)&h0s[del] = *(const f16x8*)&h0g[(size_t)(node0 + row) * 64 + chunk * 8];
        *(f16x8*)&h1s[del] = *(const f16x8*)&h1g[(size_t)(node0 + row) * 64 + chunk * 8];
    } else {
        f16x8 z = {};
        *(f16x8*)&h0s[del] = z;
        *(f16x8*)&h1s[del] = z;
    }
    if (tid < 64) xs[tid] = (node0 + tid < NN) ? hist[(size_t)(node0 + tid) * HW + t + 6] : 0.f;
    __syncthreads();

    float h0o[2][4], h1o[2][4];
    #pragma unroll
    for (int c = 0; c < 2; ++c)
        #pragma unroll
        for (int r = 0; r < 4; ++r) {
            h0o[c][r] = (float)h0s[C.wa[c][r]];
            h1o[c][r] = (float)h1s[C.wa[c][r]];
        }

    gru_step<false>(tid, l, mi, nj, h0s, h1s, xs, red, wf, C, h0o, h1o, nullptr, t, node0);

    if (tid < 64 && node0 + tid < NN) {
        const int node = node0 + tid;
        float y = red[(tid >> 4) * 32 + (tid & 15)]
                + red[(tid >> 4) * 32 + 16 + (tid & 15)] + o2b[0];
        float agg = 0.f;
        #pragma unroll
        for (int k = 0; k < DEG; ++k) agg += m_buf[node + k * NN];
        float diff = agg / nrm[node] * lin_w[0];
        float s = sigf(oparam[0]);
        float o = s * y + (1.f - s) * diff;
        dec_out[(size_t)node * TF + t] = o;
        hist[(size_t)node * HW + t + 7] = o;
    }
    if (node0 + row < NN) {
        *(f16x8*)&h0g[(size_t)(node0 + row) * 64 + chunk * 8] = *(const f16x8*)&h0s[del];
        *(f16x8*)&h1g[(size_t)(node0 + row) * 64 + chunk * 8] = *(const f16x8*)&h1s[del];
    }
}

// -------- per-node GNN layer-1 projection: u=(W1a+W1b)x+b1, v=-W1b x --------
__global__ __launch_bounds__(256)
void node_proj(int t, const float* __restrict__ hist,
               const float* __restrict__ w1, const float* __restrict__ b1,
               f16* __restrict__ uv)
{
    __shared__ float wa[64 * 8], wb[64 * 8], b1s[64];
    const int tid = threadIdx.x;
    for (int i = tid; i < 448; i += 256) {
        const int o = i / 7, c = i % 7;
        const float A = w1[o * 14 + c], B = w1[o * 14 + 7 + c];
        wa[o * 8 + c] = A + B;
        wb[o * 8 + c] = -B;
    }
    if (tid < 64) b1s[tid] = b1[tid];
    __syncthreads();
    const int n = blockIdx.x * 256 + tid;
    if (n >= NN) return;
    float x[7];
    #pragma unroll
    for (int c = 0; c < 7; ++c) x[c] = hist[(size_t)n * HW + t + c];
    #pragma unroll
    for (int half = 0; half < 2; ++half) {
        const float* wp = half ? wb : wa;
        #pragma unroll
        for (int ob = 0; ob < 8; ++ob) {
            f16x8 r;
            #pragma unroll
            for (int e = 0; e < 8; ++e) {
                const int o = ob * 8 + e;
                float a = half ? 0.f : b1s[o];
                #pragma unroll
                for (int c = 0; c < 7; ++c) a = fmaf(wp[o * 8 + c], x[c], a);
                r[e] = (f16)a;
            }
            *(f16x8*)&uv[(size_t)n * 128 + half * 64 + ob * 8] = r;
        }
    }
}

// -------- GNN edge MLP: m1=relu(u_src+v_dst); MFMA layer-2 (+b2); dot wo ----
__global__ __launch_bounds__(256)
void edge_kernel(const f16* __restrict__ uv, const int* __restrict__ eidx,
                 const float* __restrict__ ea, const f16* __restrict__ w2f,
                 const float* __restrict__ b2, const float* __restrict__ wo,
                 const float* __restrict__ bo, float* __restrict__ m_buf)
{
    __shared__ f16 m1s[256 * 64];
    const int tid = threadIdx.x;
    const int l = tid & 63;
    const int w = tid >> 6;
    const int e0 = blockIdx.x * 256;
    const int e = e0 + tid;
    const int src = eidx[e], dst = eidx[EE + e];
    const f16* up = &uv[(size_t)src * 128];
    const f16* vp = &uv[(size_t)dst * 128 + 64];

    #pragma unroll
    for (int k = 0; k < 8; ++k) {
        f16x8 u8 = *(const f16x8*)&up[k * 8];
        f16x8 v8 = *(const f16x8*)&vp[k * 8];
        f16x8 m;
        #pragma unroll
        for (int q = 0; q < 8; ++q) {
            f16 s = (f16)(u8[q] + v8[q]);
            m[q] = s > (f16)0.f ? s : (f16)0.f;
        }
        *(f16x8*)&m1s[tid * 64 + ((k ^ (tid & 7)) << 3)] = m;
    }
    __syncthreads();

    const f32x4 z4 = {0.f, 0.f, 0.f, 0.f};
    f16x8 b[2][2];
    #pragma unroll
    for (int nj = 0; nj < 2; ++nj)
        #pragma unroll
        for (int s = 0; s < 2; ++s)
            b[nj][s] = *(const f16x8*)&w2f[((nj * 2 + s) << 9) + l * 8];
    float wov[2], b2v[2];
    #pragma unroll
    for (int nj = 0; nj < 2; ++nj) {
        wov[nj] = wo[nj * 16 + (l & 15)];
        b2v[nj] = b2[nj * 16 + (l & 15)];
    }
    const float bo0 = bo[0];

    #pragma unroll
    for (int mi = 0; mi < 4; ++mi) {
        const int row = w * 64 + mi * 16 + (l & 15);
        f16x8 a[2];
        #pragma unroll
        for (int s = 0; s < 2; ++s)
            a[s] = *(const f16x8*)&m1s[row * 64 + (((s * 4 + (l >> 4)) ^ (row & 7)) << 3)];
        f32x4 acc0 = z4, acc1 = z4;
        acc0 = __builtin_amdgcn_mfma_f32_16x16x32_f16(a[0], b[0][0], acc0, 0, 0, 0);
        acc0 = __builtin_amdgcn_mfma_f32_16x16x32_f16(a[1], b[0][1], acc0, 0, 0, 0);
        acc1 = __builtin_amdgcn_mfma_f32_16x16x32_f16(a[0], b[1][0], acc1, 0, 0, 0);
        acc1 = __builtin_amdgcn_mfma_f32_16x16x32_f16(a[1], b[1][1], acc1, 0, 0, 0);
        float ps[4];
        #pragma unroll
        for (int r = 0; r < 4; ++r)
            ps[r] = fmaxf(acc0[r] + b2v[0], 0.f) * wov[0]
                  + fmaxf(acc1[r] + b2v[1], 0.f) * wov[1];
        #pragma unroll
        for (int m = 1; m < 16; m <<= 1)
            #pragma unroll
            for (int r = 0; r < 4; ++r) ps[r] += __shfl_xor(ps[r], m, 64);
        if ((l & 15) == 0) {
            const int ig = l >> 4;
            #pragma unroll
            for (int r = 0; r < 4; ++r) {
                const int e2 = e0 + w * 64 + mi * 16 + ig * 4 + r;
                m_buf[e2] = (ps[r] + bo0) * ea[e2];
            }
        }
    }
}

__global__ __launch_bounds__(256)
void norm_kernel(const float* __restrict__ ea, float* __restrict__ nrm)
{
    const int n = blockIdx.x * 256 + threadIdx.x;
    if (n >= NN) return;
    float s = 0.f;
    #pragma unroll
    for (int k = 0; k < DEG; ++k) s += ea[n + k * NN];
    nrm[n] = s;
}

extern "C" void kernel_launch(void* const* d_in, const int* in_sizes, int n_in,
                              void* d_out, int out_size, void* d_ws, size_t ws_size,
                              hipStream_t stream)
{
    const float* enc_in = (const float*)d_in[0];
    const float* ea     = (const float*)d_in[1];
    const int*   eidx   = (const int*)d_in[2];
    const float* w0i = (const float*)d_in[3];
    const float* w0h = (const float*)d_in[4];
    const float* b0i = (const float*)d_in[5];
    const float* b0h = (const float*)d_in[6];
    const float* w1i = (const float*)d_in[7];
    const float* w1h = (const float*)d_in[8];
    const float* b1i = (const float*)d_in[9];
    const float* b1h = (const float*)d_in[10];
    const float* o1w = (const float*)d_in[11];
    const float* o1b = (const float*)d_in[12];
    const float* o2w = (const float*)d_in[13];
    const float* o2b = (const float*)d_in[14];
    const float* gw1  = (const float*)d_in[15];
    const float* gb1  = (const float*)d_in[16];
    const float* gw2  = (const float*)d_in[17];
    const float* gb2  = (const float*)d_in[18];
    const float* gwo  = (const float*)d_in[19];
    const float* gbo  = (const float*)d_in[20];
    const float* glin = (const float*)d_in[21];
    const float* gop  = (const float*)d_in[22];

    float* dec_out = (float*)d_out;                 // [NN][24]
    float* enc_out = dec_out + (size_t)NN * TF;     // [NN][48]

    f16*   h0g   = (f16*)d_ws;                      // NN*64 f16
    f16*   h1g   = h0g + (size_t)NN * HD;           // NN*64 f16
    float* hist  = (float*)(h1g + (size_t)NN * HD); // NN*31 f32
    float* m_buf = hist + (size_t)NN * HW;          // EE f32
    float* nrm   = m_buf + (size_t)EE;              // NN f32
    f16*   wfrag = (f16*)(nrm + NN);                // NFRAG*512 f16
    f16*   uvb   = wfrag + (size_t)NFRAG * 512;     // NN*128 f16

    const int nblk = (NN + 63) / 64;                // 782

    pack_weights<<<(NFRAG * 64 + 255) / 256, 256, 0, stream>>>(w0h, w1i, w1h, o1w, gw2, wfrag);
    norm_kernel<<<(NN + 255) / 256, 256, 0, stream>>>(ea, nrm);
    enc_kernel<<<nblk, 512, 0, stream>>>(enc_in, w0i, b0i, b0h, b1i, b1h,
                                         o1b, o2w, o2b, wfrag,
                                         enc_out, h0g, h1g, hist);
    for (int t = 0; t < TF; ++t) {
        node_proj<<<(NN + 255) / 256, 256, 0, stream>>>(t, hist, gw1, gb1, uvb);
        edge_kernel<<<EE / 256, 256, 0, stream>>>(uvb, eidx, ea, wfrag + OFF_W2,
                                                  gb2, gwo, gbo, m_buf);
        dec_node_kernel<<<nblk, 512, 0, stream>>>(t, w0i, b0i, b0h, b1i, b1h,
                                                  o1b, o2w, o2b, wfrag,
                                                  m_buf, nrm, glin, gop,
                                                  hist, h0g, h1g, dec_out);
    }
}

// Round 5
// 3968.959 us; speedup vs baseline: 5.2908x; 1.0111x over previous
//
#include <hip/hip_runtime.h>

#define NN 50000
#define TE 48
#define TF 24
#define HD 64
#define DEG 32
#define EE (NN*DEG)
#define HW 31
#define NPB 192          // nodes per block (12 waves * 16)
#define NBLK 261         // ceil(50000/192)

// frag indices (512-f16 units) in packed buffer
#define F_W0H 0
#define F_W1I 24
#define F_W1H 48
#define F_O1W 72
#define F_GNN 80
#define NSTAGED 88
#define SPARSE_U32 576                    // 36 tiles * 16 rows
#define DENSE_BYTES (NSTAGED*1024)        // 90112
#define SPARSE_OFF DENSE_BYTES
#define STAGE_BYTES (DENSE_BYTES + SPARSE_U32*4)   // 92416
#define SCRATCH_OFF STAGE_BYTES
#define LDS_TOTAL (SCRATCH_OFF + 12*2048)          // 116992
#define W2_ELEM_OFF (STAGE_BYTES/2)                // f16 offset of W2 frags in global buf

typedef _Float16 f16;
typedef __attribute__((ext_vector_type(8))) _Float16 f16x8;
typedef __attribute__((ext_vector_type(2))) __fp16 fp16x2_builtin;
typedef __attribute__((ext_vector_type(4))) float f32x4;

__device__ __forceinline__ float sigf(float x) { return 1.f / (1.f + __expf(-x)); }
__device__ __forceinline__ float tanhfast(float x) {
    float t = __expf(-2.f * fabsf(x));
    float r = (1.f - t) / (1.f + t);
    return x < 0.f ? -r : r;
}

__device__ __forceinline__ f32x4 mf(f16x8 a, f16x8 b, f32x4 c) {
    return __builtin_amdgcn_mfma_f32_16x16x32_f16(a, b, c, 0, 0, 0);
}
__device__ __forceinline__ f16x8 ldfrag(const char* L, int f, int l) {
    return *(const f16x8*)(L + f * 1024 + l * 16);
}
__device__ __forceinline__ f16x8 spfrag(const unsigned* sp, int tt, int l, int g) {
    unsigned d = sp[tt * 16 + (l & 15)];
    if (g != 0) d = 0u;
    union { unsigned u; f16 h[2]; } c; c.u = d;
    f16x8 r = {};
    r[0] = c.h[0]; r[1] = c.h[1];
    return r;
}
__device__ __forceinline__ unsigned pk2(float a, float b) {
    fp16x2_builtin t = __builtin_amdgcn_cvt_pkrtz(a, b);
    union { fp16x2_builtin v; unsigned u; } c; c.v = t; return c.u;
}

struct WaveCtx {
    int l, g, n;
    char* S;                 // per-wave 2KB scratch
    const char* WL;          // dense frags in LDS
    const unsigned* SP;      // sparse tables in LDS
};

// one 2-layer GRU step + head for the wave's 16 nodes. No barriers.
__device__ __forceinline__ float gru16_step(const WaveCtx& W, float x,
    f16x8 (&h0B)[2], f16x8 (&h1B)[2],
    float (&h0d)[4][4], float (&h1d)[4][4],
    const float (&o2wv)[4][4])
{
    const f32x4 z4 = {0.f, 0.f, 0.f, 0.f};
    const int l = W.l, g = W.g, n = W.n;

    f16x8 xb = {};
    if (g == 0) { xb[0] = (f16)x; xb[1] = (f16)1.0f; }

    // ---------- layer 0 ----------
    #pragma unroll
    for (int nt = 0; nt < 4; ++nt) {
        f32x4 aR  = mf(spfrag(W.SP, nt,      l, g), xb, z4);
        aR  = mf(ldfrag(W.WL, F_W0H + nt*2,       l), h0B[0], aR);
        aR  = mf(ldfrag(W.WL, F_W0H + nt*2 + 1,   l), h0B[1], aR);
        f32x4 aZ  = mf(spfrag(W.SP, 4 + nt,  l, g), xb, z4);
        aZ  = mf(ldfrag(W.WL, F_W0H + (4+nt)*2,     l), h0B[0], aZ);
        aZ  = mf(ldfrag(W.WL, F_W0H + (4+nt)*2 + 1, l), h0B[1], aZ);
        f32x4 aNi = mf(spfrag(W.SP, 8 + nt,  l, g), xb, z4);
        f32x4 aNh = mf(spfrag(W.SP, 12 + nt, l, g), xb, z4);
        aNh = mf(ldfrag(W.WL, F_W0H + (8+nt)*2,     l), h0B[0], aNh);
        aNh = mf(ldfrag(W.WL, F_W0H + (8+nt)*2 + 1, l), h0B[1], aNh);
        #pragma unroll
        for (int r = 0; r < 4; ++r) {
            float rg = sigf(aR[r]);
            float zg = sigf(aZ[r]);
            float ng = tanhfast(aNi[r] + rg * aNh[r]);
            h0d[nt][r] = ng + zg * (h0d[nt][r] - ng);
        }
    }
    // transpose h0d -> scratch -> h0B (= y0 frags, also next step's h0)
    #pragma unroll
    for (int nt = 0; nt < 4; ++nt) {
        uint2 wv;
        wv.x = pk2(h0d[nt][0], h0d[nt][1]);
        wv.y = pk2(h0d[nt][2], h0d[nt][3]);
        *(uint2*)(W.S + n*128 + (((2*nt + (g >> 1)) ^ (n & 7)) * 16) + 8*(g & 1)) = wv;
    }
    #pragma unroll
    for (int s = 0; s < 2; ++s)
        h0B[s] = *(const f16x8*)(W.S + n*128 + (((4*s + g) ^ (n & 7)) * 16));

    // ---------- layer 1 ----------
    #pragma unroll
    for (int nt = 0; nt < 4; ++nt) {
        f32x4 aR  = mf(spfrag(W.SP, 16 + nt, l, g), xb, z4);
        aR  = mf(ldfrag(W.WL, F_W1I + nt*2,       l), h0B[0], aR);
        aR  = mf(ldfrag(W.WL, F_W1I + nt*2 + 1,   l), h0B[1], aR);
        aR  = mf(ldfrag(W.WL, F_W1H + nt*2,       l), h1B[0], aR);
        aR  = mf(ldfrag(W.WL, F_W1H + nt*2 + 1,   l), h1B[1], aR);
        f32x4 aZ  = mf(spfrag(W.SP, 20 + nt, l, g), xb, z4);
        aZ  = mf(ldfrag(W.WL, F_W1I + (4+nt)*2,     l), h0B[0], aZ);
        aZ  = mf(ldfrag(W.WL, F_W1I + (4+nt)*2 + 1, l), h0B[1], aZ);
        aZ  = mf(ldfrag(W.WL, F_W1H + (4+nt)*2,     l), h1B[0], aZ);
        aZ  = mf(ldfrag(W.WL, F_W1H + (4+nt)*2 + 1, l), h1B[1], aZ);
        f32x4 aNi = mf(spfrag(W.SP, 24 + nt, l, g), xb, z4);
        aNi = mf(ldfrag(W.WL, F_W1I + (8+nt)*2,     l), h0B[0], aNi);
        aNi = mf(ldfrag(W.WL, F_W1I + (8+nt)*2 + 1, l), h0B[1], aNi);
        f32x4 aNh = mf(spfrag(W.SP, 28 + nt, l, g), xb, z4);
        aNh = mf(ldfrag(W.WL, F_W1H + (8+nt)*2,     l), h1B[0], aNh);
        aNh = mf(ldfrag(W.WL, F_W1H + (8+nt)*2 + 1, l), h1B[1], aNh);
        #pragma unroll
        for (int r = 0; r < 4; ++r) {
            float rg = sigf(aR[r]);
            float zg = sigf(aZ[r]);
            float ng = tanhfast(aNi[r] + rg * aNh[r]);
            h1d[nt][r] = ng + zg * (h1d[nt][r] - ng);
        }
    }
    // transpose h1d -> scratch -> h1B (= y1 frags)
    #pragma unroll
    for (int nt = 0; nt < 4; ++nt) {
        uint2 wv;
        wv.x = pk2(h1d[nt][0], h1d[nt][1]);
        wv.y = pk2(h1d[nt][2], h1d[nt][3]);
        *(uint2*)(W.S + n*128 + (((2*nt + (g >> 1)) ^ (n & 7)) * 16) + 8*(g & 1)) = wv;
    }
    #pragma unroll
    for (int s = 0; s < 2; ++s)
        h1B[s] = *(const f16x8*)(W.S + n*128 + (((4*s + g) ^ (n & 7)) * 16));

    // ---------- head ----------
    float psum = 0.f;
    #pragma unroll
    for (int nt = 0; nt < 4; ++nt) {
        f32x4 aH = mf(spfrag(W.SP, 32 + nt, l, g), xb, z4);
        aH = mf(ldfrag(W.WL, F_O1W + nt*2,     l), h1B[0], aH);
        aH = mf(ldfrag(W.WL, F_O1W + nt*2 + 1, l), h1B[1], aH);
        #pragma unroll
        for (int r = 0; r < 4; ++r)
            psum += fmaxf(aH[r], 0.f) * o2wv[nt][r];
    }
    psum += __shfl_xor(psum, 16, 64);
    psum += __shfl_xor(psum, 32, 64);
    return psum;
}

__device__ __forceinline__ void stage_lds(char* smem, const f16* wfrag, int tid) {
    uint4* d = (uint4*)smem;
    const uint4* s = (const uint4*)wfrag;
    for (int i = tid; i < STAGE_BYTES / 16; i += 768) d[i] = s[i];
    __syncthreads();
}

// ---------------- weight packing ----------------
__global__ __launch_bounds__(256)
void pack_weights(const float* __restrict__ w0i, const float* __restrict__ w0h,
                  const float* __restrict__ b0i, const float* __restrict__ b0h,
                  const float* __restrict__ w1i, const float* __restrict__ w1h,
                  const float* __restrict__ b1i, const float* __restrict__ b1h,
                  const float* __restrict__ o1w, const float* __restrict__ o1b,
                  const float* __restrict__ gw1, const float* __restrict__ gb1,
                  const float* __restrict__ gw2,
                  f16* __restrict__ wf, unsigned* __restrict__ sp)
{
    const int i = blockIdx.x * 256 + threadIdx.x;
    if (i < 92 * 64) {
        const int f = i >> 6, l = i & 63;
        const int lr = l & 15, g = l >> 4;
        f16x8 out = {};
        if (f < F_GNN) {
            const float* src; int fb;
            if (f < F_W1I)      { src = w0h; fb = f; }
            else if (f < F_W1H) { src = w1i; fb = f - F_W1I; }
            else if (f < F_O1W) { src = w1h; fb = f - F_W1H; }
            else                { src = o1w; fb = f - F_O1W; }
            const int nt = fb >> 1, s = fb & 1;
            const int row = nt * 16 + lr, k0 = s * 32 + g * 8;
            #pragma unroll
            for (int e = 0; e < 8; ++e) out[e] = (f16)src[row * 64 + k0 + e];
            *(f16x8*)&wf[f * 512 + l * 8] = out;
        } else if (f < 88) {
            const int mt = f - F_GNN;
            const int m = mt * 16 + lr;
            #pragma unroll
            for (int e = 0; e < 8; ++e) {
                int k = g * 8 + e; float v = 0.f;
                if (m < 64) {
                    if (k < 7) v = gw1[m * 14 + k] + gw1[m * 14 + 7 + k];
                    else if (k == 7) v = gb1[m];
                } else {
                    int mm = m - 64;
                    if (k < 7) v = -gw1[mm * 14 + 7 + k];
                }
                out[e] = (f16)v;
            }
            *(f16x8*)&wf[f * 512 + l * 8] = out;
        } else {
            const int fb = f - 88, nt = fb >> 1, s = fb & 1;
            const int row = nt * 16 + lr, k0 = s * 32 + g * 8;
            #pragma unroll
            for (int e = 0; e < 8; ++e) out[e] = (f16)gw2[row * 64 + k0 + e];
            *(f16x8*)&wf[W2_ELEM_OFF + fb * 512 + l * 8] = out;
        }
    } else {
        const int e = i - 92 * 64;
        if (e < SPARSE_U32) {
            const int tt = e >> 4, r16 = e & 15;
            float c0 = 0.f, c1 = 0.f;
            if (tt < 8)       { int row = tt*16 + r16;            c0 = w0i[row]; c1 = b0i[row] + b0h[row]; }
            else if (tt < 12) { int row = 128 + (tt-8)*16 + r16;  c0 = w0i[row]; c1 = b0i[row]; }
            else if (tt < 16) { int row = 128 + (tt-12)*16 + r16; c1 = b0h[row]; }
            else if (tt < 24) { int row = (tt-16)*16 + r16;       c1 = b1i[row] + b1h[row]; }
            else if (tt < 28) { int row = 128 + (tt-24)*16 + r16; c1 = b1i[row]; }
            else if (tt < 32) { int row = 128 + (tt-28)*16 + r16; c1 = b1h[row]; }
            else              { int row = (tt-32)*16 + r16;       c1 = o1b[row]; }
            union { f16 h[2]; unsigned u; } c;
            c.h[0] = (f16)c0; c.h[1] = (f16)c1;
            sp[e] = c.u;
        }
    }
}

// ---------------- encoder ----------------
__global__ __launch_bounds__(768, 3)
void enc_kernel(const float* __restrict__ enc_in, const float* __restrict__ o2w,
                const float* __restrict__ o2b, const f16* __restrict__ wfrag,
                float* __restrict__ enc_out, f16* __restrict__ h0g, f16* __restrict__ h1g,
                float* __restrict__ hist, f16* __restrict__ uvb)
{
    extern __shared__ char smem[];
    const int tid = threadIdx.x;
    stage_lds(smem, wfrag, tid);

    WaveCtx W;
    W.l = tid & 63;
    const int wid = __builtin_amdgcn_readfirstlane(tid >> 6);
    W.g = W.l >> 4; W.n = W.l & 15;
    W.WL = smem;
    W.SP = (const unsigned*)(smem + SPARSE_OFF);
    W.S  = smem + SCRATCH_OFF + wid * 2048;

    const int node = blockIdx.x * NPB + wid * 16 + W.n;
    const bool valid = node < NN;

    float o2wv[4][4];
    #pragma unroll
    for (int nt = 0; nt < 4; ++nt)
        #pragma unroll
        for (int r = 0; r < 4; ++r)
            o2wv[nt][r] = o2w[nt * 16 + 4 * W.g + r];

    f16x8 h0B[2] = {}, h1B[2] = {};
    float h0d[4][4] = {}, h1d[4][4] = {};
    const float* pe = enc_in + (size_t)node * TE;
    const float o2b0 = o2b[0];
    float y = 0.f;

    for (int t = 0; t < TE; ++t) {
        float x = valid ? pe[t] : 0.f;
        y = gru16_step(W, x, h0B, h1B, h0d, h1d, o2wv) + o2b0;
        if (W.g == 0 && valid) enc_out[(size_t)node * TE + t] = y;
    }

    if (valid) {
        #pragma unroll
        for (int s = 0; s < 2; ++s) {
            *(f16x8*)&h0g[(size_t)node * 64 + 32 * s + 8 * W.g] = h0B[s];
            *(f16x8*)&h1g[(size_t)node * 64 + 32 * s + 8 * W.g] = h1B[s];
        }
    }
    if (W.g == 0 && valid) {
        #pragma unroll
        for (int j = 0; j < 6; ++j) hist[(size_t)node * HW + j] = pe[42 + j];
        hist[(size_t)node * HW + 6] = y;
    }
    // uv(0) via GNN projection MFMAs
    f16x8 wb = {};
    if (W.g == 0) {
        #pragma unroll
        for (int j = 0; j < 6; ++j) wb[j] = (f16)(valid ? pe[42 + j] : 0.f);
        wb[6] = (f16)y;
        wb[7] = (f16)1.0f;
    }
    const f32x4 z4 = {0.f, 0.f, 0.f, 0.f};
    #pragma unroll
    for (int mt = 0; mt < 8; ++mt) {
        f32x4 a = mf(ldfrag(W.WL, F_GNN + mt, W.l), wb, z4);
        if (valid) {
            uint2 wv; wv.x = pk2(a[0], a[1]); wv.y = pk2(a[2], a[3]);
            *(uint2*)&uvb[(size_t)node * 128 + mt * 16 + 4 * W.g] = wv;
        }
    }
}

// ---------------- decoder node step (+ fused uv projection) ----------------
__global__ __launch_bounds__(768, 3)
void dec_node_kernel(int t, const float* __restrict__ o2w, const float* __restrict__ o2b,
                     const f16* __restrict__ wfrag,
                     const float* __restrict__ m_buf, const float* __restrict__ nrm,
                     const float* __restrict__ lin_w, const float* __restrict__ oparam,
                     float* __restrict__ hist, f16* __restrict__ h0g, f16* __restrict__ h1g,
                     float* __restrict__ dec_out, f16* __restrict__ uvb)
{
    extern __shared__ char smem[];
    const int tid = threadIdx.x;
    stage_lds(smem, wfrag, tid);

    WaveCtx W;
    W.l = tid & 63;
    const int wid = __builtin_amdgcn_readfirstlane(tid >> 6);
    W.g = W.l >> 4; W.n = W.l & 15;
    W.WL = smem;
    W.SP = (const unsigned*)(smem + SPARSE_OFF);
    W.S  = smem + SCRATCH_OFF + wid * 2048;

    const int node = blockIdx.x * NPB + wid * 16 + W.n;
    const bool valid = node < NN;
    const int n = W.n, g = W.g;

    float o2wv[4][4];
    #pragma unroll
    for (int nt = 0; nt < 4; ++nt)
        #pragma unroll
        for (int r = 0; r < 4; ++r)
            o2wv[nt][r] = o2w[nt * 16 + 4 * g + r];

    // load h states (B-frag layout, [node][64] natural order)
    f16x8 h0B[2] = {}, h1B[2] = {};
    if (valid) {
        #pragma unroll
        for (int s = 0; s < 2; ++s) {
            h0B[s] = *(const f16x8*)&h0g[(size_t)node * 64 + 32 * s + 8 * g];
            h1B[s] = *(const f16x8*)&h1g[(size_t)node * 64 + 32 * s + 8 * g];
        }
    }
    // derive D-layout copies via scratch (wave-internal, no barrier)
    float h0d[4][4], h1d[4][4];
    #pragma unroll
    for (int s = 0; s < 2; ++s)
        *(f16x8*)(W.S + n*128 + (((4*s + g) ^ (n & 7)) * 16)) = h0B[s];
    #pragma unroll
    for (int nt = 0; nt < 4; ++nt) {
        union { uint2 u; f16 h[4]; } c;
        c.u = *(const uint2*)(W.S + n*128 + (((2*nt + (g >> 1)) ^ (n & 7)) * 16) + 8*(g & 1));
        #pragma unroll
        for (int r = 0; r < 4; ++r) h0d[nt][r] = (float)c.h[r];
    }
    #pragma unroll
    for (int s = 0; s < 2; ++s)
        *(f16x8*)(W.S + n*128 + (((4*s + g) ^ (n & 7)) * 16)) = h1B[s];
    #pragma unroll
    for (int nt = 0; nt < 4; ++nt) {
        union { uint2 u; f16 h[4]; } c;
        c.u = *(const uint2*)(W.S + n*128 + (((2*nt + (g >> 1)) ^ (n & 7)) * 16) + 8*(g & 1));
        #pragma unroll
        for (int r = 0; r < 4; ++r) h1d[nt][r] = (float)c.h[r];
    }

    float x = valid ? hist[(size_t)node * HW + t + 6] : 0.f;
    float y = gru16_step(W, x, h0B, h1B, h0d, h1d, o2wv) + o2b[0];

    // aggregation: 4 lanes per node sum 8 slots each, then reduce
    float agg = 0.f;
    if (valid) {
        #pragma unroll
        for (int k = 0; k < 8; ++k) agg += m_buf[node + (size_t)(g * 8 + k) * NN];
    }
    agg += __shfl_xor(agg, 16, 64);
    agg += __shfl_xor(agg, 32, 64);

    float o = 0.f;
    if (valid) {
        float diff = agg / nrm[node] * lin_w[0];
        float s = sigf(oparam[0]);
        o = s * y + (1.f - s) * diff;
        if (g == 0) {
            dec_out[(size_t)node * TF + t] = o;
            hist[(size_t)node * HW + t + 7] = o;
        }
    }

    // uv(t+1)
    f16x8 wb = {};
    if (g == 0 && valid) {
        #pragma unroll
        for (int j = 0; j < 6; ++j) wb[j] = (f16)hist[(size_t)node * HW + t + 1 + j];
        wb[6] = (f16)o;
        wb[7] = (f16)1.0f;
    }
    const f32x4 z4 = {0.f, 0.f, 0.f, 0.f};
    #pragma unroll
    for (int mt = 0; mt < 8; ++mt) {
        f32x4 a = mf(ldfrag(W.WL, F_GNN + mt, W.l), wb, z4);
        if (valid) {
            uint2 wv; wv.x = pk2(a[0], a[1]); wv.y = pk2(a[2], a[3]);
            *(uint2*)&uvb[(size_t)node * 128 + mt * 16 + 4 * g] = wv;
        }
    }
    // store h states
    if (valid) {
        #pragma unroll
        for (int s = 0; s < 2; ++s) {
            *(f16x8*)&h0g[(size_t)node * 64 + 32 * s + 8 * g] = h0B[s];
            *(f16x8*)&h1g[(size_t)node * 64 + 32 * s + 8 * g] = h1B[s];
        }
    }
}

// ---------------- GNN edge MLP (unchanged structure) ----------------
__global__ __launch_bounds__(256)
void edge_kernel(const f16* __restrict__ uv, const int* __restrict__ eidx,
                 const float* __restrict__ ea, const f16* __restrict__ w2f,
                 const float* __restrict__ b2, const float* __restrict__ wo,
                 const float* __restrict__ bo, float* __restrict__ m_buf)
{
    __shared__ f16 m1s[256 * 64];
    const int tid = threadIdx.x;
    const int l = tid & 63;
    const int w = tid >> 6;
    const int e0 = blockIdx.x * 256;
    const int e = e0 + tid;
    const int src = eidx[e], dst = eidx[EE + e];
    const f16* up = &uv[(size_t)src * 128];
    const f16* vp = &uv[(size_t)dst * 128 + 64];

    #pragma unroll
    for (int k = 0; k < 8; ++k) {
        f16x8 u8 = *(const f16x8*)&up[k * 8];
        f16x8 v8 = *(const f16x8*)&vp[k * 8];
        f16x8 m;
        #pragma unroll
        for (int q = 0; q < 8; ++q) {
            f16 s = (f16)(u8[q] + v8[q]);
            m[q] = s > (f16)0.f ? s : (f16)0.f;
        }
        *(f16x8*)&m1s[tid * 64 + ((k ^ (tid & 7)) << 3)] = m;
    }
    __syncthreads();

    const f32x4 z4 = {0.f, 0.f, 0.f, 0.f};
    f16x8 b[2][2];
    #pragma unroll
    for (int nj = 0; nj < 2; ++nj)
        #pragma unroll
        for (int s = 0; s < 2; ++s)
            b[nj][s] = *(const f16x8*)&w2f[((nj * 2 + s) << 9) + l * 8];
    float wov[2], b2v[2];
    #pragma unroll
    for (int nj = 0; nj < 2; ++nj) {
        wov[nj] = wo[nj * 16 + (l & 15)];
        b2v[nj] = b2[nj * 16 + (l & 15)];
    }
    const float bo0 = bo[0];

    #pragma unroll
    for (int mi = 0; mi < 4; ++mi) {
        const int row = w * 64 + mi * 16 + (l & 15);
        f16x8 a[2];
        #pragma unroll
        for (int s = 0; s < 2; ++s)
            a[s] = *(const f16x8*)&m1s[row * 64 + (((s * 4 + (l >> 4)) ^ (row & 7)) << 3)];
        f32x4 acc0 = z4, acc1 = z4;
        acc0 = mf(a[0], b[0][0], acc0);
        acc0 = mf(a[1], b[0][1], acc0);
        acc1 = mf(a[0], b[1][0], acc1);
        acc1 = mf(a[1], b[1][1], acc1);
        float ps[4];
        #pragma unroll
        for (int r = 0; r < 4; ++r)
            ps[r] = fmaxf(acc0[r] + b2v[0], 0.f) * wov[0]
                  + fmaxf(acc1[r] + b2v[1], 0.f) * wov[1];
        #pragma unroll
        for (int m = 1; m < 16; m <<= 1)
            #pragma unroll
            for (int r = 0; r < 4; ++r) ps[r] += __shfl_xor(ps[r], m, 64);
        if ((l & 15) == 0) {
            const int ig = l >> 4;
            #pragma unroll
            for (int r = 0; r < 4; ++r) {
                const int e2 = e0 + w * 64 + mi * 16 + ig * 4 + r;
                m_buf[e2] = (ps[r] + bo0) * ea[e2];
            }
        }
    }
}

__global__ __launch_bounds__(256)
void norm_kernel(const float* __restrict__ ea, float* __restrict__ nrm)
{
    const int nd = blockIdx.x * 256 + threadIdx.x;
    if (nd >= NN) return;
    float s = 0.f;
    #pragma unroll
    for (int k = 0; k < DEG; ++k) s += ea[nd + k * NN];
    nrm[nd] = s;
}

extern "C" void kernel_launch(void* const* d_in, const int* in_sizes, int n_in,
                              void* d_out, int out_size, void* d_ws, size_t ws_size,
                              hipStream_t stream)
{
    const float* enc_in = (const float*)d_in[0];
    const float* ea     = (const float*)d_in[1];
    const int*   eidx   = (const int*)d_in[2];
    const float* w0i = (const float*)d_in[3];
    const float* w0h = (const float*)d_in[4];
    const float* b0i = (const float*)d_in[5];
    const float* b0h = (const float*)d_in[6];
    const float* w1i = (const float*)d_in[7];
    const float* w1h = (const float*)d_in[8];
    const float* b1i = (const float*)d_in[9];
    const float* b1h = (const float*)d_in[10];
    const float* o1w = (const float*)d_in[11];
    const float* o1b = (const float*)d_in[12];
    const float* o2w = (const float*)d_in[13];
    const float* o2b = (const float*)d_in[14];
    const float* gw1  = (const float*)d_in[15];
    const float* gb1  = (const float*)d_in[16];
    const float* gw2  = (const float*)d_in[17];
    const float* gb2  = (const float*)d_in[18];
    const float* gwo  = (const float*)d_in[19];
    const float* gbo  = (const float*)d_in[20];
    const float* glin = (const float*)d_in[21];
    const float* gop  = (const float*)d_in[22];

    float* dec_out = (float*)d_out;                 // [NN][24]
    float* enc_out = dec_out + (size_t)NN * TF;     // [NN][48]

    // workspace
    char* ws = (char*)d_ws;
    f16*      wfrag = (f16*)ws;                               // 96512 B (88 dense + sparse + W2)
    unsigned* sp    = (unsigned*)(ws + SPARSE_OFF);
    f16*      w2f   = wfrag + W2_ELEM_OFF;
    char* p = ws + 96512;
    f16*   uvb   = (f16*)p;        p += (size_t)NN * 128 * 2;
    f16*   h0g   = (f16*)p;        p += (size_t)NN * 64 * 2;
    f16*   h1g   = (f16*)p;        p += (size_t)NN * 64 * 2;
    float* hist  = (float*)p;      p += (size_t)NN * HW * 4;
    float* m_buf = (float*)p;      p += (size_t)EE * 4;
    float* nrm   = (float*)p;

    (void)hipFuncSetAttribute((const void*)enc_kernel,
                        hipFuncAttributeMaxDynamicSharedMemorySize, LDS_TOTAL);
    (void)hipFuncSetAttribute((const void*)dec_node_kernel,
                        hipFuncAttributeMaxDynamicSharedMemorySize, LDS_TOTAL);

    pack_weights<<<(92 * 64 + SPARSE_U32 + 255) / 256, 256, 0, stream>>>(
        w0i, w0h, b0i, b0h, w1i, w1h, b1i, b1h, o1w, o1b, gw1, gb1, gw2, wfrag, sp);
    norm_kernel<<<(NN + 255) / 256, 256, 0, stream>>>(ea, nrm);
    enc_kernel<<<NBLK, 768, LDS_TOTAL, stream>>>(enc_in, o2w, o2b, wfrag,
                                                 enc_out, h0g, h1g, hist, uvb);
    for (int t = 0; t < TF; ++t) {
        edge_kernel<<<EE / 256, 256, 0, stream>>>(uvb, eidx, ea, w2f,
                                                  gb2, gwo, gbo, m_buf);
        dec_node_kernel<<<NBLK, 768, LDS_TOTAL, stream>>>(t, o2w, o2b, wfrag,
                                                          m_buf, nrm, glin, gop,
                                                          hist, h0g, h1g, dec_out, uvb);
    }
}

// Round 6
// 3344.483 us; speedup vs baseline: 6.2787x; 1.1867x over previous
//
#include <hip/hip_runtime.h>
#include <hip/hip_cooperative_groups.h>

#define NN 50000
#define TE 48
#define TF 24
#define DEG 32
#define EE (NN*DEG)
#define NW 8             // waves per block
#define NPW 32           // nodes per wave (2 groups of 16)
#define NPB 256          // nodes per block
#define NBLK 196         // 196*256 = 50176 >= 50000; <= 256 co-resident blocks

// staged-LDS layout (bytes)
#define F_W0H 0
#define F_W1I 24
#define F_W1H 48
#define F_O1W 72
#define F_GNN 80
#define DENSE_BYTES (88*1024)                 // 90112
#define SPARSE_OFF DENSE_BYTES
#define SPARSE_U32 576                        // 36 tiles * 16 rows
#define W2_OFF (SPARSE_OFF + SPARSE_U32*4)    // 92416
#define W2_ELEM_OFF (W2_OFF/2)                // f16 index of W2 frags
#define EXTRA_OFF (W2_OFF + 4096)             // 96512: f32 table b2[32],wo[32],o2w[64]
#define STAGE_BYTES (EXTRA_OFF + 512)         // 97024
#define SCRATCH_OFF STAGE_BYTES
#define WAVE_SCRATCH 4096                     // 32 nodes * 128B
#define LDS_TOTAL (SCRATCH_OFF + NW*WAVE_SCRATCH)   // 129792

typedef _Float16 f16;
typedef __attribute__((ext_vector_type(8))) _Float16 f16x8;
typedef __attribute__((ext_vector_type(2))) __fp16 fp16x2_builtin;
typedef __attribute__((ext_vector_type(4))) float f32x4;

__device__ __forceinline__ float sigf(float x) { return 1.f / (1.f + __expf(-x)); }
__device__ __forceinline__ float tanhfast(float x) {
    float t = __expf(-2.f * fabsf(x));
    float r = (1.f - t) / (1.f + t);
    return x < 0.f ? -r : r;
}
__device__ __forceinline__ f32x4 mf(f16x8 a, f16x8 b, f32x4 c) {
    return __builtin_amdgcn_mfma_f32_16x16x32_f16(a, b, c, 0, 0, 0);
}
__device__ __forceinline__ f16x8 ldfrag(const char* L, int f, int l) {
    return *(const f16x8*)(L + f * 1024 + l * 16);
}
__device__ __forceinline__ f16x8 spfrag(const unsigned* sp, int tt, int l, int g) {
    unsigned d = sp[tt * 16 + (l & 15)];
    if (g != 0) d = 0u;
    union { unsigned u; f16 h[2]; } c; c.u = d;
    f16x8 r = {};
    r[0] = c.h[0]; r[1] = c.h[1];
    return r;
}
__device__ __forceinline__ unsigned pk2(float a, float b) {
    fp16x2_builtin t = __builtin_amdgcn_cvt_pkrtz(a, b);
    union { fp16x2_builtin v; unsigned u; } c; c.v = t; return c.u;
}

struct Wctx {
    int l, g, n;
    char* S;                  // per-wave 4KB scratch
    const char* WL;           // dense frags in LDS
    const unsigned* SP;       // sparse tables
    const float* XT;          // f32 table: b2, wo, o2w
};

// D-layout 4 values -> scratch (node row nn, tile nt)
__device__ __forceinline__ void wr_d4(const Wctx& W, int nn, int nt, const float* d) {
    uint2 wv; wv.x = pk2(d[0], d[1]); wv.y = pk2(d[2], d[3]);
    *(uint2*)(W.S + nn * 128 + (((2 * nt + (W.g >> 1)) ^ (nn & 7)) * 16) + 8 * (W.g & 1)) = wv;
}
__device__ __forceinline__ f16x8 rd_b(const Wctx& W, int nn, int s) {
    return *(const f16x8*)(W.S + nn * 128 + (((4 * s + W.g) ^ (nn & 7)) * 16));
}

// One 2-layer GRU step + output head for the wave's 32 nodes (2 groups). No barriers.
__device__ __forceinline__ void gru32_step(const Wctx& W, const float* xv,
    f16x8 (&h0B)[2][2], f16x8 (&h1B)[2][2],
    float (&h0d)[2][4][4], float (&h1d)[2][4][4], float* yv)
{
    const f32x4 z4 = {0.f, 0.f, 0.f, 0.f};
    f16x8 xb[2];
    #pragma unroll
    for (int q = 0; q < 2; ++q) {
        f16x8 e = {};
        if (W.g == 0) { e[0] = (f16)xv[q]; e[1] = (f16)1.0f; }
        xb[q] = e;
    }
    // ---------- layer 0 ----------
    #pragma unroll
    for (int nt = 0; nt < 4; ++nt) {
        f16x8 wR0 = ldfrag(W.WL, F_W0H + nt * 2,       W.l);
        f16x8 wR1 = ldfrag(W.WL, F_W0H + nt * 2 + 1,   W.l);
        f16x8 wZ0 = ldfrag(W.WL, F_W0H + (4 + nt) * 2,     W.l);
        f16x8 wZ1 = ldfrag(W.WL, F_W0H + (4 + nt) * 2 + 1, W.l);
        f16x8 wN0 = ldfrag(W.WL, F_W0H + (8 + nt) * 2,     W.l);
        f16x8 wN1 = ldfrag(W.WL, F_W0H + (8 + nt) * 2 + 1, W.l);
        f16x8 sR  = spfrag(W.SP, nt,      W.l, W.g);
        f16x8 sZ  = spfrag(W.SP, 4 + nt,  W.l, W.g);
        f16x8 sNi = spfrag(W.SP, 8 + nt,  W.l, W.g);
        f16x8 sNh = spfrag(W.SP, 12 + nt, W.l, W.g);
        #pragma unroll
        for (int q = 0; q < 2; ++q) {
            f32x4 aR = mf(sR, xb[q], z4);
            aR = mf(wR0, h0B[q][0], aR); aR = mf(wR1, h0B[q][1], aR);
            f32x4 aZ = mf(sZ, xb[q], z4);
            aZ = mf(wZ0, h0B[q][0], aZ); aZ = mf(wZ1, h0B[q][1], aZ);
            f32x4 aNi = mf(sNi, xb[q], z4);
            f32x4 aNh = mf(sNh, xb[q], z4);
            aNh = mf(wN0, h0B[q][0], aNh); aNh = mf(wN1, h0B[q][1], aNh);
            #pragma unroll
            for (int r = 0; r < 4; ++r) {
                float rg = sigf(aR[r]);
                float zg = sigf(aZ[r]);
                float ng = tanhfast(aNi[r] + rg * aNh[r]);
                h0d[q][nt][r] = ng + zg * (h0d[q][nt][r] - ng);
            }
        }
    }
    #pragma unroll
    for (int q = 0; q < 2; ++q)
        #pragma unroll
        for (int nt = 0; nt < 4; ++nt) wr_d4(W, q * 16 + W.n, nt, h0d[q][nt]);
    #pragma unroll
    for (int q = 0; q < 2; ++q)
        #pragma unroll
        for (int s = 0; s < 2; ++s) h0B[q][s] = rd_b(W, q * 16 + W.n, s);

    // ---------- layer 1 ----------
    #pragma unroll
    for (int nt = 0; nt < 4; ++nt) {
        f16x8 iR0 = ldfrag(W.WL, F_W1I + nt * 2,       W.l);
        f16x8 iR1 = ldfrag(W.WL, F_W1I + nt * 2 + 1,   W.l);
        f16x8 hR0 = ldfrag(W.WL, F_W1H + nt * 2,       W.l);
        f16x8 hR1 = ldfrag(W.WL, F_W1H + nt * 2 + 1,   W.l);
        f16x8 iZ0 = ldfrag(W.WL, F_W1I + (4 + nt) * 2,     W.l);
        f16x8 iZ1 = ldfrag(W.WL, F_W1I + (4 + nt) * 2 + 1, W.l);
        f16x8 hZ0 = ldfrag(W.WL, F_W1H + (4 + nt) * 2,     W.l);
        f16x8 hZ1 = ldfrag(W.WL, F_W1H + (4 + nt) * 2 + 1, W.l);
        f16x8 iN0 = ldfrag(W.WL, F_W1I + (8 + nt) * 2,     W.l);
        f16x8 iN1 = ldfrag(W.WL, F_W1I + (8 + nt) * 2 + 1, W.l);
        f16x8 hN0 = ldfrag(W.WL, F_W1H + (8 + nt) * 2,     W.l);
        f16x8 hN1 = ldfrag(W.WL, F_W1H + (8 + nt) * 2 + 1, W.l);
        f16x8 sR  = spfrag(W.SP, 16 + nt, W.l, W.g);
        f16x8 sZ  = spfrag(W.SP, 20 + nt, W.l, W.g);
        f16x8 sNi = spfrag(W.SP, 24 + nt, W.l, W.g);
        f16x8 sNh = spfrag(W.SP, 28 + nt, W.l, W.g);
        #pragma unroll
        for (int q = 0; q < 2; ++q) {
            f32x4 aR = mf(sR, xb[q], z4);
            aR = mf(iR0, h0B[q][0], aR); aR = mf(iR1, h0B[q][1], aR);
            aR = mf(hR0, h1B[q][0], aR); aR = mf(hR1, h1B[q][1], aR);
            f32x4 aZ = mf(sZ, xb[q], z4);
            aZ = mf(iZ0, h0B[q][0], aZ); aZ = mf(iZ1, h0B[q][1], aZ);
            aZ = mf(hZ0, h1B[q][0], aZ); aZ = mf(hZ1, h1B[q][1], aZ);
            f32x4 aNi = mf(sNi, xb[q], z4);
            aNi = mf(iN0, h0B[q][0], aNi); aNi = mf(iN1, h0B[q][1], aNi);
            f32x4 aNh = mf(sNh, xb[q], z4);
            aNh = mf(hN0, h1B[q][0], aNh); aNh = mf(hN1, h1B[q][1], aNh);
            #pragma unroll
            for (int r = 0; r < 4; ++r) {
                float rg = sigf(aR[r]);
                float zg = sigf(aZ[r]);
                float ng = tanhfast(aNi[r] + rg * aNh[r]);
                h1d[q][nt][r] = ng + zg * (h1d[q][nt][r] - ng);
            }
        }
    }
    #pragma unroll
    for (int q = 0; q < 2; ++q)
        #pragma unroll
        for (int nt = 0; nt < 4; ++nt) wr_d4(W, q * 16 + W.n, nt, h1d[q][nt]);
    #pragma unroll
    for (int q = 0; q < 2; ++q)
        #pragma unroll
        for (int s = 0; s < 2; ++s) h1B[q][s] = rd_b(W, q * 16 + W.n, s);

    // ---------- head ----------
    yv[0] = 0.f; yv[1] = 0.f;
    #pragma unroll
    for (int nt = 0; nt < 4; ++nt) {
        f16x8 o0 = ldfrag(W.WL, F_O1W + nt * 2,     W.l);
        f16x8 o1 = ldfrag(W.WL, F_O1W + nt * 2 + 1, W.l);
        f16x8 sO = spfrag(W.SP, 32 + nt, W.l, W.g);
        f32x4 ow = *(const f32x4*)(W.XT + 64 + nt * 16 + W.g * 4);
        #pragma unroll
        for (int q = 0; q < 2; ++q) {
            f32x4 aH = mf(sO, xb[q], z4);
            aH = mf(o0, h1B[q][0], aH);
            aH = mf(o1, h1B[q][1], aH);
            #pragma unroll
            for (int r = 0; r < 4; ++r)
                yv[q] += fmaxf(aH[r], 0.f) * ow[r];
        }
    }
    #pragma unroll
    for (int q = 0; q < 2; ++q) {
        yv[q] += __shfl_xor(yv[q], 16, 64);
        yv[q] += __shfl_xor(yv[q], 32, 64);
    }
}

// GNN projection: x7 -> u (store to global, B-layout per node) + v (keep in regs)
__device__ __forceinline__ void project_uv(const Wctx& W, const float (&win)[2][7],
    const bool (&valid)[2], const int (&node)[2], f16* __restrict__ ubw,
    f16x8 (&v0)[2], f16x8 (&v1)[2])
{
    const f32x4 z4 = {0.f, 0.f, 0.f, 0.f};
    f16x8 xw[2];
    #pragma unroll
    for (int q = 0; q < 2; ++q) {
        f16x8 e = {};
        if (W.g == 0) {
            #pragma unroll
            for (int j = 0; j < 7; ++j) e[j] = (f16)win[q][j];
            e[7] = (f16)1.0f;
        }
        xw[q] = e;
    }
    // u tiles (rows 0..63)
    #pragma unroll
    for (int q = 0; q < 2; ++q) {
        const int nn = q * 16 + W.n;
        #pragma unroll
        for (int mt = 0; mt < 4; ++mt) {
            f32x4 a = mf(ldfrag(W.WL, F_GNN + mt, W.l), xw[q], z4);
            uint2 wv; wv.x = pk2(a[0], a[1]); wv.y = pk2(a[2], a[3]);
            *(uint2*)(W.S + nn * 128 + ((mt ^ (nn & 3)) * 32) + W.g * 8) = wv;
        }
    }
    #pragma unroll
    for (int q = 0; q < 2; ++q) {
        const int nn = q * 16 + W.n;
        uint4 lo = *(const uint4*)(W.S + nn * 128 + ((W.g ^ (nn & 3)) * 32));
        uint4 hi = *(const uint4*)(W.S + nn * 128 + ((W.g ^ (nn & 3)) * 32) + 16);
        if (valid[q]) {
            *(uint4*)&ubw[(size_t)node[q] * 64 + W.g * 16]     = lo;
            *(uint4*)&ubw[(size_t)node[q] * 64 + W.g * 16 + 8] = hi;
        }
    }
    // v tiles (rows 64..127) — reuse scratch (wave-internal ordering)
    #pragma unroll
    for (int q = 0; q < 2; ++q) {
        const int nn = q * 16 + W.n;
        #pragma unroll
        for (int mt = 0; mt < 4; ++mt) {
            f32x4 a = mf(ldfrag(W.WL, F_GNN + 4 + mt, W.l), xw[q], z4);
            uint2 wv; wv.x = pk2(a[0], a[1]); wv.y = pk2(a[2], a[3]);
            *(uint2*)(W.S + nn * 128 + ((mt ^ (nn & 3)) * 32) + W.g * 8) = wv;
        }
    }
    #pragma unroll
    for (int q = 0; q < 2; ++q) {
        const int nn = q * 16 + W.n;
        v0[q] = *(const f16x8*)(W.S + nn * 128 + ((((W.g >> 1))     ^ (nn & 3)) * 32) + (W.g & 1) * 16);
        v1[q] = *(const f16x8*)(W.S + nn * 128 + (((2 + (W.g >> 1)) ^ (nn & 3)) * 32) + (W.g & 1) * 16);
    }
}

// ---------------- weight packing ----------------
__global__ __launch_bounds__(256)
void pack_weights(const float* __restrict__ w0i, const float* __restrict__ w0h,
                  const float* __restrict__ b0i, const float* __restrict__ b0h,
                  const float* __restrict__ w1i, const float* __restrict__ w1h,
                  const float* __restrict__ b1i, const float* __restrict__ b1h,
                  const float* __restrict__ o1w, const float* __restrict__ o1b,
                  const float* __restrict__ gw1, const float* __restrict__ gb1,
                  const float* __restrict__ gw2, const float* __restrict__ gb2,
                  const float* __restrict__ gwo, const float* __restrict__ o2w,
                  f16* __restrict__ wf, unsigned* __restrict__ sp)
{
    const int i = blockIdx.x * 256 + threadIdx.x;
    if (i < 92 * 64) {
        const int f = i >> 6, l = i & 63;
        const int lr = l & 15, g = l >> 4;
        f16x8 out = {};
        if (f < F_GNN) {
            const float* src; int fb;
            if (f < F_W1I)      { src = w0h; fb = f; }
            else if (f < F_W1H) { src = w1i; fb = f - F_W1I; }
            else if (f < F_O1W) { src = w1h; fb = f - F_W1H; }
            else                { src = o1w; fb = f - F_O1W; }
            const int nt = fb >> 1, s = fb & 1;
            const int row = nt * 16 + lr, k0 = s * 32 + g * 8;
            #pragma unroll
            for (int e = 0; e < 8; ++e) out[e] = (f16)src[row * 64 + k0 + e];
            *(f16x8*)&wf[f * 512 + l * 8] = out;
        } else if (f < 88) {
            const int mt = f - F_GNN;
            const int m = mt * 16 + lr;
            #pragma unroll
            for (int e = 0; e < 8; ++e) {
                int k = g * 8 + e; float v = 0.f;
                if (m < 64) {
                    if (k < 7) v = gw1[m * 14 + k] + gw1[m * 14 + 7 + k];
                    else if (k == 7) v = gb1[m];
                } else {
                    int mm = m - 64;
                    if (k < 7) v = -gw1[mm * 14 + 7 + k];
                }
                out[e] = (f16)v;
            }
            *(f16x8*)&wf[f * 512 + l * 8] = out;
        } else {
            const int fb = f - 88, nt = fb >> 1, s = fb & 1;
            const int row = nt * 16 + lr, k0 = s * 32 + g * 8;
            #pragma unroll
            for (int e = 0; e < 8; ++e) out[e] = (f16)gw2[row * 64 + k0 + e];
            *(f16x8*)&wf[W2_ELEM_OFF + fb * 512 + l * 8] = out;
        }
    } else {
        const int e = i - 92 * 64;
        if (e < SPARSE_U32) {
            const int tt = e >> 4, r16 = e & 15;
            float c0 = 0.f, c1 = 0.f;
            if (tt < 8)       { int row = tt*16 + r16;            c0 = w0i[row]; c1 = b0i[row] + b0h[row]; }
            else if (tt < 12) { int row = 128 + (tt-8)*16 + r16;  c0 = w0i[row]; c1 = b0i[row]; }
            else if (tt < 16) { int row = 128 + (tt-12)*16 + r16; c1 = b0h[row]; }
            else if (tt < 24) { int row = (tt-16)*16 + r16;       c1 = b1i[row] + b1h[row]; }
            else if (tt < 28) { int row = 128 + (tt-24)*16 + r16; c1 = b1i[row]; }
            else if (tt < 32) { int row = 128 + (tt-28)*16 + r16; c1 = b1h[row]; }
            else              { int row = (tt-32)*16 + r16;       c1 = o1b[row]; }
            union { f16 h[2]; unsigned u; } c;
            c.h[0] = (f16)c0; c.h[1] = (f16)c1;
            sp[e] = c.u;
        } else if (e < SPARSE_U32 + 128) {
            const int idx = e - SPARSE_U32;
            float v;
            if (idx < 32) v = gb2[idx];
            else if (idx < 64) v = gwo[idx - 32];
            else v = o2w[idx - 64];
            float* xf = (float*)((char*)wf + EXTRA_OFF);
            xf[idx] = v;
        }
    }
}

// ---------------- the fused cooperative kernel ----------------
__global__ __launch_bounds__(512, 2)
void fused_kernel(const float* __restrict__ enc_in, const int* __restrict__ eidx,
                  const float* __restrict__ ea,
                  const float* __restrict__ o2b, const float* __restrict__ oparam,
                  const float* __restrict__ lin_w, const float* __restrict__ bo,
                  const f16* __restrict__ wfrag,
                  float* __restrict__ enc_out, float* __restrict__ dec_out,
                  f16* __restrict__ ub0, f16* __restrict__ ub1)
{
    extern __shared__ char smem[];
    const int tid = threadIdx.x;
    {
        uint4* d = (uint4*)smem;
        const uint4* s4 = (const uint4*)wfrag;
        for (int i = tid; i < STAGE_BYTES / 16; i += 512) d[i] = s4[i];
    }
    __syncthreads();

    Wctx W;
    W.l = tid & 63;
    const int wid = __builtin_amdgcn_readfirstlane(tid >> 6);
    W.g = W.l >> 4; W.n = W.l & 15;
    W.WL = smem;
    W.SP = (const unsigned*)(smem + SPARSE_OFF);
    W.XT = (const float*)(smem + EXTRA_OFF);
    W.S  = smem + SCRATCH_OFF + wid * WAVE_SCRATCH;

    const f32x4 z4 = {0.f, 0.f, 0.f, 0.f};

    int node[2]; bool valid[2]; int ndc[2];
    #pragma unroll
    for (int q = 0; q < 2; ++q) {
        node[q] = blockIdx.x * NPB + wid * NPW + q * 16 + W.n;
        valid[q] = node[q] < NN;
        ndc[q] = valid[q] ? node[q] : NN - 1;
    }

    const float o2b0 = o2b[0];
    const float sv = sigf(oparam[0]);
    const float lw = lin_w[0];
    const float bo0 = bo[0];

    f16x8 Aw2[2][2];
    #pragma unroll
    for (int nj = 0; nj < 2; ++nj)
        #pragma unroll
        for (int s = 0; s < 2; ++s)
            Aw2[nj][s] = *(const f16x8*)(smem + W2_OFF + (nj * 2 + s) * 1024 + W.l * 16);

    float invc[2];
    #pragma unroll
    for (int q = 0; q < 2; ++q) {
        float nr = 0.f;
        #pragma unroll
        for (int kk = 0; kk < 8; ++kk) nr += ea[(size_t)(W.g * 8 + kk) * NN + ndc[q]];
        nr += __shfl_xor(nr, 16, 64);
        nr += __shfl_xor(nr, 32, 64);
        invc[q] = (1.f - sv) * lw / nr;
    }

    // ---------------- encoder: 48 steps ----------------
    f16x8 h0B[2][2] = {}, h1B[2][2] = {};
    float h0d[2][4][4] = {}, h1d[2][4][4] = {};
    float win[2][7];
    float yv[2];
    {
        const float* pe0 = enc_in + (size_t)ndc[0] * TE;
        const float* pe1 = enc_in + (size_t)ndc[1] * TE;
        for (int t = 0; t < TE; ++t) {
            float xv[2] = { pe0[t], pe1[t] };
            gru32_step(W, xv, h0B, h1B, h0d, h1d, yv);
            #pragma unroll
            for (int q = 0; q < 2; ++q) {
                yv[q] += o2b0;
                if (W.g == 0 && valid[q]) enc_out[(size_t)node[q] * TE + t] = yv[q];
            }
        }
        #pragma unroll
        for (int q = 0; q < 2; ++q) {
            const float* pe = q ? pe1 : pe0;
            #pragma unroll
            for (int j = 0; j < 6; ++j) win[q][j] = pe[42 + j];
            win[q][6] = yv[q];
        }
    }
    f16x8 v0[2], v1[2];
    project_uv(W, win, valid, node, ub0, v0, v1);

    // ---------------- decoder: 24 steps ----------------
    for (int t = 0; t < TF; ++t) {
        cooperative_groups::this_grid().sync();
        const f16* ub = (t & 1) ? ub1 : ub0;
        f16*      ubw = (t & 1) ? ub0 : ub1;

        // edge phase: 32 slots per node, fully in-register aggregation
        f32x4 b2r0 = *(const f32x4*)(W.XT + 0  + W.g * 4);
        f32x4 b2r1 = *(const f32x4*)(W.XT + 16 + W.g * 4);
        f32x4 wor0 = *(const f32x4*)(W.XT + 32 + W.g * 4);
        f32x4 wor1 = *(const f32x4*)(W.XT + 48 + W.g * 4);
        float agg[2] = { 0.f, 0.f };
        #pragma unroll 2
        for (int k = 0; k < DEG; ++k) {
            #pragma unroll
            for (int q = 0; q < 2; ++q) {
                const int e = k * NN + ndc[q];
                const int srcn = eidx[e];
                const f16* up = ub + (size_t)srcn * 64;
                f16x8 u0 = *(const f16x8*)(up + W.g * 8);
                f16x8 u1 = *(const f16x8*)(up + 32 + W.g * 8);
                f16x8 m0, m1;
                #pragma unroll
                for (int j = 0; j < 8; ++j) {
                    f16 a = u0[j] + v0[q][j]; m0[j] = a > (f16)0.f ? a : (f16)0.f;
                    f16 b = u1[j] + v1[q][j]; m1[j] = b > (f16)0.f ? b : (f16)0.f;
                }
                f32x4 acc0 = mf(Aw2[0][0], m0, z4); acc0 = mf(Aw2[0][1], m1, acc0);
                f32x4 acc1 = mf(Aw2[1][0], m0, z4); acc1 = mf(Aw2[1][1], m1, acc1);
                float ps = 0.f;
                #pragma unroll
                for (int r = 0; r < 4; ++r)
                    ps += fmaxf(acc0[r] + b2r0[r], 0.f) * wor0[r]
                        + fmaxf(acc1[r] + b2r1[r], 0.f) * wor1[r];
                ps += __shfl_xor(ps, 16, 64);
                ps += __shfl_xor(ps, 32, 64);
                agg[q] += (ps + bo0) * ea[e];
            }
        }

        // GRU step (x = y_prev)
        float xv[2] = { win[0][6], win[1][6] };
        gru32_step(W, xv, h0B, h1B, h0d, h1d, yv);

        #pragma unroll
        for (int q = 0; q < 2; ++q) {
            float o = sv * (yv[q] + o2b0) + agg[q] * invc[q];
            if (W.g == 0 && valid[q]) dec_out[(size_t)node[q] * TF + t] = o;
            #pragma unroll
            for (int j = 0; j < 6; ++j) win[q][j] = win[q][j + 1];
            win[q][6] = o;
        }
        if (t < TF - 1) project_uv(W, win, valid, node, ubw, v0, v1);
    }
}

extern "C" void kernel_launch(void* const* d_in, const int* in_sizes, int n_in,
                              void* d_out, int out_size, void* d_ws, size_t ws_size,
                              hipStream_t stream)
{
    const float* enc_in = (const float*)d_in[0];
    const float* ea     = (const float*)d_in[1];
    const int*   eidx   = (const int*)d_in[2];
    const float* w0i = (const float*)d_in[3];
    const float* w0h = (const float*)d_in[4];
    const float* b0i = (const float*)d_in[5];
    const float* b0h = (const float*)d_in[6];
    const float* w1i = (const float*)d_in[7];
    const float* w1h = (const float*)d_in[8];
    const float* b1i = (const float*)d_in[9];
    const float* b1h = (const float*)d_in[10];
    const float* o1w = (const float*)d_in[11];
    const float* o1b = (const float*)d_in[12];
    const float* o2w = (const float*)d_in[13];
    const float* o2b = (const float*)d_in[14];
    const float* gw1  = (const float*)d_in[15];
    const float* gb1  = (const float*)d_in[16];
    const float* gw2  = (const float*)d_in[17];
    const float* gb2  = (const float*)d_in[18];
    const float* gwo  = (const float*)d_in[19];
    const float* gbo  = (const float*)d_in[20];
    const float* glin = (const float*)d_in[21];
    const float* gop  = (const float*)d_in[22];

    float* dec_out = (float*)d_out;                 // [NN][24]
    float* enc_out = dec_out + (size_t)NN * TF;     // [NN][48]

    char* ws = (char*)d_ws;
    f16*      wfrag = (f16*)ws;
    unsigned* sp    = (unsigned*)(ws + SPARSE_OFF);
    f16* ub0 = (f16*)(ws + ((STAGE_BYTES + 255) & ~255));
    f16* ub1 = ub0 + (size_t)NN * 64;

    (void)hipFuncSetAttribute((const void*)fused_kernel,
        hipFuncAttributeMaxDynamicSharedMemorySize, LDS_TOTAL);

    pack_weights<<<(92 * 64 + SPARSE_U32 + 128 + 255) / 256, 256, 0, stream>>>(
        w0i, w0h, b0i, b0h, w1i, w1h, b1i, b1h, o1w, o1b,
        gw1, gb1, gw2, gb2, gwo, o2w, wfrag, sp);

    void* args[] = {
        (void*)&enc_in, (void*)&eidx, (void*)&ea,
        (void*)&o2b, (void*)&gop, (void*)&glin, (void*)&gbo,
        (void*)&wfrag, (void*)&enc_out, (void*)&dec_out,
        (void*)&ub0, (void*)&ub1
    };
    (void)hipLaunchCooperativeKernel((const void*)fused_kernel, dim3(NBLK), dim3(512),
                                     args, LDS_TOTAL, stream);
}

// Round 7
// 2410.409 us; speedup vs baseline: 8.7118x; 1.3875x over previous
//
#include <hip/hip_runtime.h>
#include <hip/hip_cooperative_groups.h>

#define NN 50000
#define TE 48
#define TF 24
#define DEG 32
#define EE (NN*DEG)
#define NW 14            // waves per block
#define NPW 16           // nodes per wave
#define NPB (NW*NPW)     // 224 nodes per block
#define NBLK 224         // 224*224 = 50176 >= 50000; 1 block/CU, 224 <= 256 CUs

// global packed-weight buffer layout (bytes) — unchanged from R6
#define F_W0H 0
#define F_W1I 24
#define F_W1H 48
#define F_O1W 72
#define F_GNN 80
#define DENSE_BYTES (88*1024)                 // 90112
#define SPARSE_OFF DENSE_BYTES
#define SPARSE_U32 576
#define W2_OFF (SPARSE_OFF + SPARSE_U32*4)    // 92416
#define W2_ELEM_OFF (W2_OFF/2)
#define EXTRA_OFF (W2_OFF + 4096)             // 96512: f32 b2[32], wo[32], o2w[64]
#define GBUF_BYTES (EXTRA_OFF + 512)          // 97024

// LDS layout (bytes): dense+sparse staged, then extra f32 table, then scratch
#define L_SPARSE_OFF DENSE_BYTES              // 90112
#define L_EXTRA_OFF  (L_SPARSE_OFF + SPARSE_U32*4)   // 92416
#define L_SCRATCH_OFF (L_EXTRA_OFF + 512)     // 92928
#define WAVE_SCRATCH 2048                     // 16 nodes * 128B
#define LDS_TOTAL (L_SCRATCH_OFF + NW*WAVE_SCRATCH)  // 121600

typedef _Float16 f16;
typedef __attribute__((ext_vector_type(8))) _Float16 f16x8;
typedef __attribute__((ext_vector_type(2))) __fp16 fp16x2_builtin;
typedef __attribute__((ext_vector_type(4))) float f32x4;

__device__ __forceinline__ float frcp(float x) { return __builtin_amdgcn_rcpf(x); }
__device__ __forceinline__ float sigf(float x) { return frcp(1.f + __expf(-x)); }
__device__ __forceinline__ float tanhfast(float x) {
    float e = __expf(-2.f * fabsf(x));
    float r = (1.f - e) * frcp(1.f + e);
    return copysignf(r, x);
}
__device__ __forceinline__ f32x4 mf(f16x8 a, f16x8 b, f32x4 c) {
    return __builtin_amdgcn_mfma_f32_16x16x32_f16(a, b, c, 0, 0, 0);
}
__device__ __forceinline__ f16x8 ldfrag(const char* L, int f, int l) {
    return *(const f16x8*)(L + f * 1024 + l * 16);
}
__device__ __forceinline__ f16x8 spfrag(const unsigned* sp, int tt, int l, int g) {
    unsigned d = sp[tt * 16 + (l & 15)];
    if (g != 0) d = 0u;
    union { unsigned u; f16 h[2]; } c; c.u = d;
    f16x8 r = {};
    r[0] = c.h[0]; r[1] = c.h[1];
    return r;
}
__device__ __forceinline__ unsigned pk2(float a, float b) {
    fp16x2_builtin t = __builtin_amdgcn_cvt_pkrtz(a, b);
    union { fp16x2_builtin v; unsigned u; } c; c.v = t; return c.u;
}
__device__ __forceinline__ void upk2(unsigned u, float& a, float& b) {
    union { unsigned uu; f16 h[2]; } c; c.uu = u;
    a = (float)c.h[0]; b = (float)c.h[1];
}

struct Wctx {
    int l, g, n;
    char* S;                  // per-wave 2KB scratch
    const char* WL;           // dense frags in LDS
    const unsigned* SP;       // sparse tables in LDS
    const float* XT;          // f32 table: b2, wo, o2w
};

// One 2-layer GRU step + output head for the wave's 16 nodes. No barriers.
// h_old kept packed f16 (uint2 per 4 rows); returns head output y.
__device__ __forceinline__ float gru16_step(const Wctx& W, float x,
    f16x8 (&h0B)[2], f16x8 (&h1B)[2], uint2 (&h0p)[4], uint2 (&h1p)[4])
{
    const f32x4 z4 = {0.f, 0.f, 0.f, 0.f};
    const int l = W.l, g = W.g, n = W.n;
    f16x8 xb = {};
    if (g == 0) { xb[0] = (f16)x; xb[1] = (f16)1.0f; }

    // ---------- layer 0 ----------
    #pragma unroll
    for (int nt = 0; nt < 4; ++nt) {
        f32x4 aR = mf(spfrag(W.SP, nt, l, g), xb, z4);
        aR = mf(ldfrag(W.WL, F_W0H + nt * 2,     l), h0B[0], aR);
        aR = mf(ldfrag(W.WL, F_W0H + nt * 2 + 1, l), h0B[1], aR);
        f32x4 aZ = mf(spfrag(W.SP, 4 + nt, l, g), xb, z4);
        aZ = mf(ldfrag(W.WL, F_W0H + (4 + nt) * 2,     l), h0B[0], aZ);
        aZ = mf(ldfrag(W.WL, F_W0H + (4 + nt) * 2 + 1, l), h0B[1], aZ);
        f32x4 aNi = mf(spfrag(W.SP, 8 + nt, l, g), xb, z4);
        f32x4 aNh = mf(spfrag(W.SP, 12 + nt, l, g), xb, z4);
        aNh = mf(ldfrag(W.WL, F_W0H + (8 + nt) * 2,     l), h0B[0], aNh);
        aNh = mf(ldfrag(W.WL, F_W0H + (8 + nt) * 2 + 1, l), h0B[1], aNh);
        float ho[4], hn[4];
        upk2(h0p[nt].x, ho[0], ho[1]);
        upk2(h0p[nt].y, ho[2], ho[3]);
        #pragma unroll
        for (int r = 0; r < 4; ++r) {
            float rg = sigf(aR[r]);
            float zg = sigf(aZ[r]);
            float ng = tanhfast(aNi[r] + rg * aNh[r]);
            hn[r] = ng + zg * (ho[r] - ng);
        }
        h0p[nt].x = pk2(hn[0], hn[1]);
        h0p[nt].y = pk2(hn[2], hn[3]);
        *(uint2*)(W.S + n * 128 + (((2 * nt + (g >> 1)) ^ (n & 7)) * 16) + 8 * (g & 1)) = h0p[nt];
    }
    #pragma unroll
    for (int s = 0; s < 2; ++s)
        h0B[s] = *(const f16x8*)(W.S + n * 128 + (((4 * s + g) ^ (n & 7)) * 16));

    // ---------- layer 1 ----------
    #pragma unroll
    for (int nt = 0; nt < 4; ++nt) {
        f32x4 aR = mf(spfrag(W.SP, 16 + nt, l, g), xb, z4);
        aR = mf(ldfrag(W.WL, F_W1I + nt * 2,     l), h0B[0], aR);
        aR = mf(ldfrag(W.WL, F_W1I + nt * 2 + 1, l), h0B[1], aR);
        aR = mf(ldfrag(W.WL, F_W1H + nt * 2,     l), h1B[0], aR);
        aR = mf(ldfrag(W.WL, F_W1H + nt * 2 + 1, l), h1B[1], aR);
        f32x4 aZ = mf(spfrag(W.SP, 20 + nt, l, g), xb, z4);
        aZ = mf(ldfrag(W.WL, F_W1I + (4 + nt) * 2,     l), h0B[0], aZ);
        aZ = mf(ldfrag(W.WL, F_W1I + (4 + nt) * 2 + 1, l), h0B[1], aZ);
        aZ = mf(ldfrag(W.WL, F_W1H + (4 + nt) * 2,     l), h1B[0], aZ);
        aZ = mf(ldfrag(W.WL, F_W1H + (4 + nt) * 2 + 1, l), h1B[1], aZ);
        f32x4 aNi = mf(spfrag(W.SP, 24 + nt, l, g), xb, z4);
        aNi = mf(ldfrag(W.WL, F_W1I + (8 + nt) * 2,     l), h0B[0], aNi);
        aNi = mf(ldfrag(W.WL, F_W1I + (8 + nt) * 2 + 1, l), h0B[1], aNi);
        f32x4 aNh = mf(spfrag(W.SP, 28 + nt, l, g), xb, z4);
        aNh = mf(ldfrag(W.WL, F_W1H + (8 + nt) * 2,     l), h1B[0], aNh);
        aNh = mf(ldfrag(W.WL, F_W1H + (8 + nt) * 2 + 1, l), h1B[1], aNh);
        float ho[4], hn[4];
        upk2(h1p[nt].x, ho[0], ho[1]);
        upk2(h1p[nt].y, ho[2], ho[3]);
        #pragma unroll
        for (int r = 0; r < 4; ++r) {
            float rg = sigf(aR[r]);
            float zg = sigf(aZ[r]);
            float ng = tanhfast(aNi[r] + rg * aNh[r]);
            hn[r] = ng + zg * (ho[r] - ng);
        }
        h1p[nt].x = pk2(hn[0], hn[1]);
        h1p[nt].y = pk2(hn[2], hn[3]);
        *(uint2*)(W.S + n * 128 + (((2 * nt + (g >> 1)) ^ (n & 7)) * 16) + 8 * (g & 1)) = h1p[nt];
    }
    #pragma unroll
    for (int s = 0; s < 2; ++s)
        h1B[s] = *(const f16x8*)(W.S + n * 128 + (((4 * s + g) ^ (n & 7)) * 16));

    // ---------- head ----------
    float y = 0.f;
    #pragma unroll
    for (int nt = 0; nt < 4; ++nt) {
        f32x4 aH = mf(spfrag(W.SP, 32 + nt, l, g), xb, z4);
        aH = mf(ldfrag(W.WL, F_O1W + nt * 2,     l), h1B[0], aH);
        aH = mf(ldfrag(W.WL, F_O1W + nt * 2 + 1, l), h1B[1], aH);
        f32x4 ow = *(const f32x4*)(W.XT + 64 + nt * 16 + g * 4);
        #pragma unroll
        for (int r = 0; r < 4; ++r)
            y += fmaxf(aH[r], 0.f) * ow[r];
    }
    y += __shfl_xor(y, 16, 64);
    y += __shfl_xor(y, 32, 64);
    return y;
}

// GNN projection: x7 -> u (to global, [node][64] f16) + v (kept in regs, B-frag layout)
__device__ __forceinline__ void project_uv(const Wctx& W, const float (&win)[7],
    bool valid, int node, f16* __restrict__ ubw, f16x8& v0, f16x8& v1)
{
    const f32x4 z4 = {0.f, 0.f, 0.f, 0.f};
    const int g = W.g, n = W.n;
    f16x8 xw = {};
    if (g == 0) {
        #pragma unroll
        for (int j = 0; j < 7; ++j) xw[j] = (f16)win[j];
        xw[7] = (f16)1.0f;
    }
    // u tiles (rows 0..63)
    #pragma unroll
    for (int mt = 0; mt < 4; ++mt) {
        f32x4 a = mf(ldfrag(W.WL, F_GNN + mt, W.l), xw, z4);
        uint2 wv; wv.x = pk2(a[0], a[1]); wv.y = pk2(a[2], a[3]);
        *(uint2*)(W.S + n * 128 + ((mt ^ (n & 3)) * 32) + g * 8) = wv;
    }
    {
        uint4 lo = *(const uint4*)(W.S + n * 128 + ((g ^ (n & 3)) * 32));
        uint4 hi = *(const uint4*)(W.S + n * 128 + ((g ^ (n & 3)) * 32) + 16);
        if (valid) {
            *(uint4*)&ubw[(size_t)node * 64 + g * 16]     = lo;
            *(uint4*)&ubw[(size_t)node * 64 + g * 16 + 8] = hi;
        }
    }
    // v tiles (rows 64..127)
    #pragma unroll
    for (int mt = 0; mt < 4; ++mt) {
        f32x4 a = mf(ldfrag(W.WL, F_GNN + 4 + mt, W.l), xw, z4);
        uint2 wv; wv.x = pk2(a[0], a[1]); wv.y = pk2(a[2], a[3]);
        *(uint2*)(W.S + n * 128 + ((mt ^ (n & 3)) * 32) + g * 8) = wv;
    }
    v0 = *(const f16x8*)(W.S + n * 128 + ((((g >> 1))     ^ (n & 3)) * 32) + (g & 1) * 16);
    v1 = *(const f16x8*)(W.S + n * 128 + (((2 + (g >> 1)) ^ (n & 3)) * 32) + (g & 1) * 16);
}

// ---------------- weight packing (unchanged layout from R6) ----------------
__global__ __launch_bounds__(256)
void pack_weights(const float* __restrict__ w0i, const float* __restrict__ w0h,
                  const float* __restrict__ b0i, const float* __restrict__ b0h,
                  const float* __restrict__ w1i, const float* __restrict__ w1h,
                  const float* __restrict__ b1i, const float* __restrict__ b1h,
                  const float* __restrict__ o1w, const float* __restrict__ o1b,
                  const float* __restrict__ gw1, const float* __restrict__ gb1,
                  const float* __restrict__ gw2, const float* __restrict__ gb2,
                  const float* __restrict__ gwo, const float* __restrict__ o2w,
                  f16* __restrict__ wf, unsigned* __restrict__ sp)
{
    const int i = blockIdx.x * 256 + threadIdx.x;
    if (i < 92 * 64) {
        const int f = i >> 6, l = i & 63;
        const int lr = l & 15, g = l >> 4;
        f16x8 out = {};
        if (f < F_GNN) {
            const float* src; int fb;
            if (f < F_W1I)      { src = w0h; fb = f; }
            else if (f < F_W1H) { src = w1i; fb = f - F_W1I; }
            else if (f < F_O1W) { src = w1h; fb = f - F_W1H; }
            else                { src = o1w; fb = f - F_O1W; }
            const int nt = fb >> 1, s = fb & 1;
            const int row = nt * 16 + lr, k0 = s * 32 + g * 8;
            #pragma unroll
            for (int e = 0; e < 8; ++e) out[e] = (f16)src[row * 64 + k0 + e];
            *(f16x8*)&wf[f * 512 + l * 8] = out;
        } else if (f < 88) {
            const int mt = f - F_GNN;
            const int m = mt * 16 + lr;
            #pragma unroll
            for (int e = 0; e < 8; ++e) {
                int k = g * 8 + e; float v = 0.f;
                if (m < 64) {
                    if (k < 7) v = gw1[m * 14 + k] + gw1[m * 14 + 7 + k];
                    else if (k == 7) v = gb1[m];
                } else {
                    int mm = m - 64;
                    if (k < 7) v = -gw1[mm * 14 + 7 + k];
                }
                out[e] = (f16)v;
            }
            *(f16x8*)&wf[f * 512 + l * 8] = out;
        } else {
            const int fb = f - 88, nt = fb >> 1, s = fb & 1;
            const int row = nt * 16 + lr, k0 = s * 32 + g * 8;
            #pragma unroll
            for (int e = 0; e < 8; ++e) out[e] = (f16)gw2[row * 64 + k0 + e];
            *(f16x8*)&wf[W2_ELEM_OFF + fb * 512 + l * 8] = out;
        }
    } else {
        const int e = i - 92 * 64;
        if (e < SPARSE_U32) {
            const int tt = e >> 4, r16 = e & 15;
            float c0 = 0.f, c1 = 0.f;
            if (tt < 8)       { int row = tt*16 + r16;            c0 = w0i[row]; c1 = b0i[row] + b0h[row]; }
            else if (tt < 12) { int row = 128 + (tt-8)*16 + r16;  c0 = w0i[row]; c1 = b0i[row]; }
            else if (tt < 16) { int row = 128 + (tt-12)*16 + r16; c1 = b0h[row]; }
            else if (tt < 24) { int row = (tt-16)*16 + r16;       c1 = b1i[row] + b1h[row]; }
            else if (tt < 28) { int row = 128 + (tt-24)*16 + r16; c1 = b1i[row]; }
            else if (tt < 32) { int row = 128 + (tt-28)*16 + r16; c1 = b1h[row]; }
            else              { int row = (tt-32)*16 + r16;       c1 = o1b[row]; }
            union { f16 h[2]; unsigned u; } c;
            c.h[0] = (f16)c0; c.h[1] = (f16)c1;
            sp[e] = c.u;
        } else if (e < SPARSE_U32 + 128) {
            const int idx = e - SPARSE_U32;
            float v;
            if (idx < 32) v = gb2[idx];
            else if (idx < 64) v = gwo[idx - 32];
            else v = o2w[idx - 64];
            float* xf = (float*)((char*)wf + EXTRA_OFF);
            xf[idx] = v;
        }
    }
}

// ---------------- fused cooperative kernel ----------------
__global__ __launch_bounds__(896, 4)
void fused_kernel(const float* __restrict__ enc_in, const int* __restrict__ eidx,
                  const float* __restrict__ ea,
                  const float* __restrict__ o2b, const float* __restrict__ oparam,
                  const float* __restrict__ lin_w, const float* __restrict__ bo,
                  const f16* __restrict__ wfrag,
                  float* __restrict__ enc_out, float* __restrict__ dec_out,
                  f16* __restrict__ ub0, f16* __restrict__ ub1)
{
    extern __shared__ char smem[];
    const int tid = threadIdx.x;
    {
        // stage dense+sparse [0, 92416) and extra table [EXTRA_OFF, +512)
        uint4* d = (uint4*)smem;
        const uint4* s4 = (const uint4*)wfrag;
        for (int i = tid; i < L_EXTRA_OFF / 16; i += 896) d[i] = s4[i];
        if (tid < 32) {
            uint4* de = (uint4*)(smem + L_EXTRA_OFF);
            const uint4* se = (const uint4*)((const char*)wfrag + EXTRA_OFF);
            de[tid] = se[tid];
        }
    }
    __syncthreads();

    Wctx W;
    W.l = tid & 63;
    const int wid = __builtin_amdgcn_readfirstlane(tid >> 6);
    W.g = W.l >> 4; W.n = W.l & 15;
    W.WL = smem;
    W.SP = (const unsigned*)(smem + L_SPARSE_OFF);
    W.XT = (const float*)(smem + L_EXTRA_OFF);
    W.S  = smem + L_SCRATCH_OFF + wid * WAVE_SCRATCH;

    const f32x4 z4 = {0.f, 0.f, 0.f, 0.f};
    const int g = W.g;

    const int node = blockIdx.x * NPB + wid * NPW + W.n;
    const bool valid = node < NN;
    const int ndc = valid ? node : NN - 1;

    const float o2b0 = o2b[0];
    const float sv = sigf(oparam[0]);
    const float bo0 = bo[0];

    f16x8 Aw2[2][2];
    #pragma unroll
    for (int nj = 0; nj < 2; ++nj)
        #pragma unroll
        for (int s = 0; s < 2; ++s)
            Aw2[nj][s] = *(const f16x8*)&wfrag[W2_ELEM_OFF + (nj * 2 + s) * 512 + W.l * 8];

    float invc;
    {
        float nr = 0.f;
        #pragma unroll
        for (int kk = 0; kk < 8; ++kk) nr += ea[(size_t)(g * 8 + kk) * NN + ndc];
        nr += __shfl_xor(nr, 16, 64);
        nr += __shfl_xor(nr, 32, 64);
        invc = (1.f - sv) * lin_w[0] * frcp(nr);
    }

    // ---------------- encoder: 48 steps ----------------
    f16x8 h0B[2] = {}, h1B[2] = {};
    uint2 h0p[4] = {}, h1p[4] = {};
    float win[7];
    float y = 0.f;
    {
        const float* pe = enc_in + (size_t)ndc * TE;
        for (int t = 0; t < TE; ++t) {
            y = gru16_step(W, pe[t], h0B, h1B, h0p, h1p) + o2b0;
            if (g == 0 && valid) enc_out[(size_t)node * TE + t] = y;
        }
        #pragma unroll
        for (int j = 0; j < 6; ++j) win[j] = pe[42 + j];
        win[6] = y;
    }
    f16x8 v0, v1;
    project_uv(W, win, valid, node, ub0, v0, v1);

    // ---------------- decoder: 24 steps ----------------
    for (int t = 0; t < TF; ++t) {
        cooperative_groups::this_grid().sync();
        const f16* ub = (t & 1) ? ub1 : ub0;
        f16*      ubw = (t & 1) ? ub0 : ub1;

        f32x4 b2r0 = *(const f32x4*)(W.XT + 0  + g * 4);
        f32x4 b2r1 = *(const f32x4*)(W.XT + 16 + g * 4);
        f32x4 wor0 = *(const f32x4*)(W.XT + 32 + g * 4);
        f32x4 wor1 = *(const f32x4*)(W.XT + 48 + g * 4);
        float agg = 0.f;
        #pragma unroll 2
        for (int k = 0; k < DEG; ++k) {
            const int e = k * NN + ndc;
            const int srcn = eidx[e];
            const f16* up = ub + (size_t)srcn * 64;
            f16x8 u0 = *(const f16x8*)(up + g * 8);
            f16x8 u1 = *(const f16x8*)(up + 32 + g * 8);
            f16x8 m0, m1;
            #pragma unroll
            for (int j = 0; j < 8; ++j) {
                f16 a = u0[j] + v0[j]; m0[j] = a > (f16)0.f ? a : (f16)0.f;
                f16 b = u1[j] + v1[j]; m1[j] = b > (f16)0.f ? b : (f16)0.f;
            }
            f32x4 acc0 = mf(Aw2[0][0], m0, z4); acc0 = mf(Aw2[0][1], m1, acc0);
            f32x4 acc1 = mf(Aw2[1][0], m0, z4); acc1 = mf(Aw2[1][1], m1, acc1);
            float ps = 0.f;
            #pragma unroll
            for (int r = 0; r < 4; ++r)
                ps += fmaxf(acc0[r] + b2r0[r], 0.f) * wor0[r]
                    + fmaxf(acc1[r] + b2r1[r], 0.f) * wor1[r];
            ps += __shfl_xor(ps, 16, 64);
            ps += __shfl_xor(ps, 32, 64);
            agg += (ps + bo0) * ea[e];
        }

        y = gru16_step(W, win[6], h0B, h1B, h0p, h1p) + o2b0;

        float o = sv * y + agg * invc;
        if (g == 0 && valid) dec_out[(size_t)node * TF + t] = o;
        #pragma unroll
        for (int j = 0; j < 6; ++j) win[j] = win[j + 1];
        win[6] = o;

        if (t < TF - 1) project_uv(W, win, valid, node, ubw, v0, v1);
    }
}

extern "C" void kernel_launch(void* const* d_in, const int* in_sizes, int n_in,
                              void* d_out, int out_size, void* d_ws, size_t ws_size,
                              hipStream_t stream)
{
    const float* enc_in = (const float*)d_in[0];
    const float* ea     = (const float*)d_in[1];
    const int*   eidx   = (const int*)d_in[2];
    const float* w0i = (const float*)d_in[3];
    const float* w0h = (const float*)d_in[4];
    const float* b0i = (const float*)d_in[5];
    const float* b0h = (const float*)d_in[6];
    const float* w1i = (const float*)d_in[7];
    const float* w1h = (const float*)d_in[8];
    const float* b1i = (const float*)d_in[9];
    const float* b1h = (const float*)d_in[10];
    const float* o1w = (const float*)d_in[11];
    const float* o1b = (const float*)d_in[12];
    const float* o2w = (const float*)d_in[13];
    const float* o2b = (const float*)d_in[14];
    const float* gw1  = (const float*)d_in[15];
    const float* gb1  = (const float*)d_in[16];
    const float* gw2  = (const float*)d_in[17];
    const float* gb2  = (const float*)d_in[18];
    const float* gwo  = (const float*)d_in[19];
    const float* gbo  = (const float*)d_in[20];
    const float* glin = (const float*)d_in[21];
    const float* gop  = (const float*)d_in[22];

    float* dec_out = (float*)d_out;                 // [NN][24]
    float* enc_out = dec_out + (size_t)NN * TF;     // [NN][48]

    char* ws = (char*)d_ws;
    f16*      wfrag = (f16*)ws;
    unsigned* sp    = (unsigned*)(ws + SPARSE_OFF);
    f16* ub0 = (f16*)(ws + ((GBUF_BYTES + 255) & ~255));
    f16* ub1 = ub0 + (size_t)NN * 64;

    (void)hipFuncSetAttribute((const void*)fused_kernel,
        hipFuncAttributeMaxDynamicSharedMemorySize, LDS_TOTAL);

    pack_weights<<<(92 * 64 + SPARSE_U32 + 128 + 255) / 256, 256, 0, stream>>>(
        w0i, w0h, b0i, b0h, w1i, w1h, b1i, b1h, o1w, o1b,
        gw1, gb1, gw2, gb2, gwo, o2w, wfrag, sp);

    void* args[] = {
        (void*)&enc_in, (void*)&eidx, (void*)&ea,
        (void*)&o2b, (void*)&gop, (void*)&glin, (void*)&gbo,
        (void*)&wfrag, (void*)&enc_out, (void*)&dec_out,
        (void*)&ub0, (void*)&ub1
    };
    (void)hipLaunchCooperativeKernel((const void*)fused_kernel, dim3(NBLK), dim3(896),
                                     args, LDS_TOTAL, stream);
}